// Round 10
// baseline (577.082 us; speedup 1.0000x reference)
//
#include <hip/hip_runtime.h>
#include <hip/hip_bf16.h>
#include <math.h>

#define NHEAD 4
#define HC 256

typedef short short8 __attribute__((ext_vector_type(8)));
typedef short short4v __attribute__((ext_vector_type(4)));
typedef float f32x4 __attribute__((ext_vector_type(4)));

__device__ inline f32x4 bf4_to_f32(short4v v)
{
  f32x4 r;
#pragma unroll
  for (int i = 0; i < 4; ++i)
    r[i] = __uint_as_float(((unsigned)(unsigned short)v[i]) << 16);
  return r;
}

__device__ inline float bf_to_f32(unsigned short u)
{
  return __uint_as_float(((unsigned)u) << 16);
}

// ------- one fused prep kernel: fp32->bf16 conversions, weight transposes,
// desc/dW zero-padded to K=224, and the degree count (grid-partitioned) -------
__global__ void prep_kernel(
    const float* __restrict__ x, const float* __restrict__ fp,
    const float* __restrict__ c1Wl, const float* __restrict__ c1Wr,
    const float* __restrict__ c2Wl, const float* __restrict__ c2Wr,
    const float* __restrict__ desc, const float* __restrict__ dW,
    const int* __restrict__ dst, int* __restrict__ deg,
    __hip_bfloat16* __restrict__ xbf, __hip_bfloat16* __restrict__ fpbf,
    __hip_bfloat16* __restrict__ wt1, __hip_bfloat16* __restrict__ wt2,
    __hip_bfloat16* __restrict__ descbf, __hip_bfloat16* __restrict__ dwt,
    int N, int G, int E, int DIN)
{
  const int n0 = N * 32, n1 = G * 2048, n2 = 512 * 32, n3 = 512 * 256;
  const int n4 = G * 224, n5 = 64 * 224;
  int idx = blockIdx.x * 256 + threadIdx.x;
  if (idx < n0) { xbf[idx] = __float2bfloat16(x[idx]); return; }
  idx -= n0;
  if (idx < n1) { fpbf[idx] = __float2bfloat16(fp[idx]); return; }
  idx -= n1;
  if (idx < n2) {
    int n = idx / 32, k = idx - n * 32;
    float v = (n < 256) ? c1Wl[k * 256 + n] : c1Wr[k * 256 + (n - 256)];
    wt1[idx] = __float2bfloat16(v); return;
  }
  idx -= n2;
  if (idx < n3) {
    int n = idx / 256, k = idx - n * 256;
    float v = (n < 256) ? c2Wl[k * 256 + n] : c2Wr[k * 256 + (n - 256)];
    wt2[idx] = __float2bfloat16(v); return;
  }
  idx -= n3;
  if (idx < n4) {
    int row = idx / 224, kp = idx - row * 224;
    float v = (kp < DIN) ? desc[(long)row * DIN + kp] : 0.f;
    descbf[idx] = __float2bfloat16(v); return;
  }
  idx -= n4;
  if (idx < n5) {
    int n = idx / 224, kp = idx - n * 224;
    float v = (kp < DIN) ? dW[kp * 64 + n] : 0.f;
    dwt[idx] = __float2bfloat16(v); return;
  }
  idx -= n5;
  if (idx < E) atomicAdd(&deg[dst[idx]], 1);
}

// ------- LDS-tiled transpose: fW[2048][256] f32 -> fwt[256][2048] bf16 -------
__global__ __launch_bounds__(256) void transpose_fwt_kernel(
    const float* __restrict__ fW, __hip_bfloat16* __restrict__ fwt)
{
  __shared__ float tile[64][65];
  int bk = blockIdx.x * 64, bn = blockIdx.y * 64;
  int tx = threadIdx.x & 63, ty = threadIdx.x >> 6;
#pragma unroll
  for (int j = 0; j < 16; ++j) {
    int kl = ty + j * 4;
    tile[kl][tx] = fW[(long)(bk + kl) * 256 + bn + tx];
  }
  __syncthreads();
#pragma unroll
  for (int j = 0; j < 16; ++j) {
    int nl = ty + j * 4;
    fwt[(long)(bn + nl) * 2048 + bk + tx] = __float2bfloat16(tile[tx][nl]);
  }
}

// ------- bf16 MFMA GEMM: [xl|xr] = A[M][K] @ W[K][512] + bias -> bf16 tables
// Tile 128(M) x 128(N); grid (M/128, 4). Halves A re-fetch vs 64-col tiles.
__global__ __launch_bounds__(256) void gemm_mfma_kernel(
    const __hip_bfloat16* __restrict__ A, const __hip_bfloat16* __restrict__ BT,
    const float* __restrict__ bl, const float* __restrict__ br,
    __hip_bfloat16* __restrict__ XL, __hip_bfloat16* __restrict__ XR, int M, int K)
{
  __shared__ short As[128 * 40];
  __shared__ short Bs[128 * 40];
  int bm = blockIdx.x * 128, bn = blockIdx.y * 128;
  int t = threadIdx.x;
  int w = t >> 6, l = t & 63;
  int quad = l >> 4, l16 = l & 15;
  int srow = t >> 1, scol = (t & 1) * 16;

  f32x4 acc[2][8];
#pragma unroll
  for (int i = 0; i < 2; ++i)
#pragma unroll
    for (int j = 0; j < 8; ++j) acc[i][j] = (f32x4){0.f, 0.f, 0.f, 0.f};

  for (int k0 = 0; k0 < K; k0 += 32) {
    *(short8*)&As[srow * 40 + scol] =
        *(const short8*)(const void*)&A[(long)(bm + srow) * K + k0 + scol];
    *(short8*)&As[srow * 40 + scol + 8] =
        *(const short8*)(const void*)&A[(long)(bm + srow) * K + k0 + scol + 8];
    *(short8*)&Bs[srow * 40 + scol] =
        *(const short8*)(const void*)&BT[(long)(bn + srow) * K + k0 + scol];
    *(short8*)&Bs[srow * 40 + scol + 8] =
        *(const short8*)(const void*)&BT[(long)(bn + srow) * K + k0 + scol + 8];
    __syncthreads();
    short8 af[2], bf[8];
#pragma unroll
    for (int mt = 0; mt < 2; ++mt)
      af[mt] = *(short8*)&As[(w * 32 + mt * 16 + l16) * 40 + quad * 8];
#pragma unroll
    for (int nt = 0; nt < 8; ++nt)
      bf[nt] = *(short8*)&Bs[(nt * 16 + l16) * 40 + quad * 8];
#pragma unroll
    for (int mt = 0; mt < 2; ++mt)
#pragma unroll
      for (int nt = 0; nt < 8; ++nt)
        acc[mt][nt] = __builtin_amdgcn_mfma_f32_16x16x32_bf16(af[mt], bf[nt], acc[mt][nt], 0, 0, 0);
    __syncthreads();
  }
#pragma unroll
  for (int mt = 0; mt < 2; ++mt)
#pragma unroll
    for (int nt = 0; nt < 8; ++nt) {
      int col = bn + nt * 16 + l16;
      float b = (col < 256) ? bl[col] : br[col - 256];
#pragma unroll
      for (int r = 0; r < 4; ++r) {
        int row = bm + w * 32 + mt * 16 + quad * 4 + r;
        float v = acc[mt][nt][r] + b;
        if (col < 256)
          XL[(long)row * 256 + col] = __float2bfloat16(v);
        else
          XR[(long)row * 256 + (col - 256)] = __float2bfloat16(v);
      }
    }
}

// ------- bf16 MFMA GEMM + relu + bn epilogue -> bf16 at out[row*ldc+coloff+col]
// A[M][K] bf16, BT[N][K] bf16 n-major. Tile 64x64, grid (M/64, N/64).
__global__ __launch_bounds__(256) void gemm_rb_kernel(
    const __hip_bfloat16* __restrict__ A, const __hip_bfloat16* __restrict__ BT,
    const float* __restrict__ bias, const float* __restrict__ gamma,
    const float* __restrict__ beta, __hip_bfloat16* __restrict__ out,
    int M, int K, int ldc, int coloff)
{
  __shared__ short As[64 * 40];
  __shared__ short Bs[64 * 40];
  int bm = blockIdx.x * 64, bn = blockIdx.y * 64;
  int t = threadIdx.x;
  int w = t >> 6, l = t & 63;
  int quad = l >> 4, l16 = l & 15;
  int lrow = t >> 2, col8 = (t & 3) * 8;

  f32x4 acc[4];
#pragma unroll
  for (int nt = 0; nt < 4; ++nt) acc[nt] = (f32x4){0.f, 0.f, 0.f, 0.f};

  for (int k0 = 0; k0 < K; k0 += 32) {
    *(short8*)&As[lrow * 40 + col8] =
        *(const short8*)(const void*)&A[(long)(bm + lrow) * K + k0 + col8];
    *(short8*)&Bs[lrow * 40 + col8] =
        *(const short8*)(const void*)&BT[(long)(bn + lrow) * K + k0 + col8];
    __syncthreads();
    short8 af = *(short8*)&As[(w * 16 + l16) * 40 + quad * 8];
#pragma unroll
    for (int nt = 0; nt < 4; ++nt) {
      short8 bf = *(short8*)&Bs[(nt * 16 + l16) * 40 + quad * 8];
      acc[nt] = __builtin_amdgcn_mfma_f32_16x16x32_bf16(af, bf, acc[nt], 0, 0, 0);
    }
    __syncthreads();
  }
  const float inv = rsqrtf(1.f + 1e-5f);
#pragma unroll
  for (int nt = 0; nt < 4; ++nt) {
    int col = bn + nt * 16 + l16;
    float b = bias[col], gm = gamma[col] * inv, bt = beta[col];
#pragma unroll
    for (int r = 0; r < 4; ++r) {
      int row = bm + w * 16 + quad * 4 + r;
      float v = fmaxf(acc[nt][r] + b, 0.f) * gm + bt;
      out[(long)row * ldc + coloff + col] = __float2bfloat16(v);
    }
  }
}

// -------- fused pool + g branch: per-graph colmax (LDS) -> 64-col dense -----
__global__ __launch_bounds__(256) void poolg_kernel(
    const __hip_bfloat16* __restrict__ h, const float* __restrict__ gW,
    const float* __restrict__ gb, const float* __restrict__ g_gn,
    const float* __restrict__ g_bt, __hip_bfloat16* __restrict__ zbuf, int npg)
{
  __shared__ float smax[256];
  __shared__ float sred[256];
  int g = blockIdx.x, t = threadIdx.x;
  const __hip_bfloat16* base = h + (long)g * npg * HC + t;
  float m = -INFINITY;
#pragma unroll 4
  for (int i = 0; i < npg; ++i)
    m = fmaxf(m, bf_to_f32(*(const unsigned short*)&base[(long)i * HC]));
  smax[t] = m;
  __syncthreads();
  int j = t >> 2, part = t & 3;
  float sum = 0.f;
#pragma unroll 4
  for (int k = part * 64; k < part * 64 + 64; ++k)
    sum = fmaf(smax[k], gW[k * 64 + j], sum);
  sred[t] = sum;
  __syncthreads();
  if (t < 64) {
    float v = sred[t * 4] + sred[t * 4 + 1] + sred[t * 4 + 2] + sred[t * 4 + 3];
    const float inv = rsqrtf(1.f + 1e-5f);
    v = fmaxf(v + gb[t], 0.f) * (g_gn[t] * inv) + g_bt[t];
    zbuf[(long)g * 384 + t] = __float2bfloat16(v);
  }
}

// -------- fused k1+k2+k3 head: zbuf(bf16)[8 rows] -> d_out --------
__global__ __launch_bounds__(256) void head_kernel(
    const __hip_bfloat16* __restrict__ zbuf,
    const float* __restrict__ k1W, const float* __restrict__ k1b,
    const float* __restrict__ k1_gn, const float* __restrict__ k1_bt,
    const float* __restrict__ k2W, const float* __restrict__ k2b,
    const float* __restrict__ k2_gn, const float* __restrict__ k2_bt,
    const float* __restrict__ k3W, const float* __restrict__ k3b,
    float* __restrict__ out)
{
  __shared__ float s0[8 * 384];
  __shared__ float s1[8 * 192];
  __shared__ float s2[8 * 96];
  int b = blockIdx.x, t = threadIdx.x;
  const float inv = rsqrtf(1.f + 1e-5f);
#pragma unroll
  for (int j = 0; j < 12; ++j) {
    int i = j * 256 + t;
    s0[i] = bf_to_f32(*(const unsigned short*)&zbuf[(long)b * 8 * 384 + i]);
  }
  __syncthreads();
#pragma unroll
  for (int j = 0; j < 6; ++j) {       // k1: 8x192 outputs
    int idx = j * 256 + t;
    int row = idx / 192, col = idx - row * 192;
    float acc = 0.f;
#pragma unroll 4
    for (int k = 0; k < 384; ++k) acc = fmaf(s0[row * 384 + k], k1W[k * 192 + col], acc);
    acc = fmaxf(acc + k1b[col], 0.f);
    s1[idx] = acc * (k1_gn[col] * inv) + k1_bt[col];
  }
  __syncthreads();
#pragma unroll
  for (int j = 0; j < 3; ++j) {       // k2: 8x96 outputs
    int idx = j * 256 + t;
    int row = idx / 96, col = idx - row * 96;
    float acc = 0.f;
#pragma unroll 4
    for (int k = 0; k < 192; ++k) acc = fmaf(s1[row * 192 + k], k2W[k * 96 + col], acc);
    acc = fmaxf(acc + k2b[col], 0.f);
    s2[idx] = acc * (k2_gn[col] * inv) + k2_bt[col];
  }
  __syncthreads();
  if (t < 96) {                        // k3: 8x12 outputs
    int row = t / 12, col = t - row * 12;
    float acc = 0.f;
#pragma unroll 4
    for (int k = 0; k < 96; ++k) acc = fmaf(s2[row * 96 + k], k3W[k * 12 + col], acc);
    out[(long)(b * 8 + row) * 12 + col] = acc + k3b[col];
  }
}

// ---------------- CSR build ----------------
__global__ __launch_bounds__(1024) void scan_kernel(
    const int* __restrict__ deg, int* __restrict__ ptr, int* __restrict__ cursor, int N)
{
  __shared__ int sums[1024];
  int t = threadIdx.x;
  int base = t * 32;
  int local[32];
  int s = 0;
#pragma unroll
  for (int i = 0; i < 32; ++i) {
    int v = (base + i < N) ? deg[base + i] : 0;
    local[i] = v; s += v;
  }
  sums[t] = s;
  __syncthreads();
  for (int off = 1; off < 1024; off <<= 1) {
    int v = (t >= off) ? sums[t - off] : 0;
    __syncthreads();
    sums[t] += v;
    __syncthreads();
  }
  int excl = sums[t] - s;
  for (int i = 0; i < 32; ++i) {
    if (base + i < N) { ptr[base + i] = excl; cursor[base + i] = excl; excl += local[i]; }
  }
  if (t == 1023) ptr[N] = sums[1023];
}

// scatter src id AND edge_attr into CSR order
__global__ void fill_kernel(const int* __restrict__ src, const int* __restrict__ dst,
                            const float* __restrict__ ea, int* __restrict__ cursor,
                            int* __restrict__ csr_src, float* __restrict__ csr_ea, int E)
{
  int e = blockIdx.x * blockDim.x + threadIdx.x;
  if (e < E) {
    int pos = atomicAdd(&cursor[dst[e]], 1);
    csr_src[pos] = src[e];
    f32x4 a0 = *(const f32x4*)(const void*)&ea[(long)e * 8];
    f32x4 a1 = *(const f32x4*)(const void*)&ea[(long)e * 8 + 4];
    *(f32x4*)&csr_ea[(long)pos * 8] = a0;
    *(f32x4*)&csr_ea[(long)pos * 8 + 4] = a1;
  }
}

// ---------------- GATv2 aggregation ----------------
// lane = head*16 + quad; lane owns 4 channels of one head; 2 nodes / 128-thr
// block. NO min-waves launch_bounds (R8: forcing 8 waves/EU -> VGPR 32 ->
// scratch spills -> 2.4 GB traffic, 8x slower). Kernel needs ~64 VGPR.
__global__ __launch_bounds__(128) void gat_kernel(
    const __hip_bfloat16* __restrict__ xlb, const __hip_bfloat16* __restrict__ xrb,
    const float* __restrict__ csr_ea, const int* __restrict__ csr_src,
    const int* __restrict__ csr_ptr,
    const float* __restrict__ We, const float* __restrict__ att,
    const float* __restrict__ bias, __hip_bfloat16* __restrict__ out, int N)
{
  int lane = threadIdx.x & 63;
  int node = blockIdx.x * 2 + (threadIdx.x >> 6);
  if (node >= N) return;
  int cbase = (lane >> 4) * 64 + (lane & 15) * 4;  // channel offset in [0,256)

  f32x4 attv = *(const f32x4*)(const void*)&att[cbase];
  f32x4 xriv = bf4_to_f32(*(const short4v*)(const void*)&xrb[(long)node * HC + cbase]);
  f32x4 biasv = *(const f32x4*)(const void*)&bias[cbase];
  f32x4 WeR[8];
#pragma unroll
  for (int d = 0; d < 8; ++d)
    WeR[d] = *(const f32x4*)(const void*)&We[d * HC + cbase];

  float rsum = 0.f;
  f32x4 acc = (f32x4){0.f, 0.f, 0.f, 0.f};
  f32x4 eas0 = (f32x4){0.f, 0.f, 0.f, 0.f};
  f32x4 eas1 = (f32x4){0.f, 0.f, 0.f, 0.f};

  int p0 = csr_ptr[node], p1 = csr_ptr[node + 1];

  auto edge_compute = [&](f32x4 xls, f32x4 ea0, f32x4 ea1) {
    f32x4 mv = xriv + xls;
#pragma unroll
    for (int d = 0; d < 4; ++d) mv += WeR[d] * ea0[d];
#pragma unroll
    for (int d = 0; d < 4; ++d) mv += WeR[d + 4] * ea1[d];
    float t = 0.f;
#pragma unroll
    for (int r = 0; r < 4; ++r) {
      float m = mv[r];
      m = (m > 0.f) ? m : 0.2f * m;
      t = fmaf(m, attv[r], t);
    }
    t += __shfl_xor(t, 1, 64);
    t += __shfl_xor(t, 2, 64);
    t += __shfl_xor(t, 4, 64);
    t += __shfl_xor(t, 8, 64);
    float p = __expf(t);
    rsum += p;
    acc += p * xls;
  };

  // 2-deep prefetch, named slots A/B (runtime-indexed arrays kill codegen)
  short4v xA = (short4v){0, 0, 0, 0}, xB = (short4v){0, 0, 0, 0};
  f32x4 a0A = (f32x4){0.f, 0.f, 0.f, 0.f}, a1A = a0A, a0B = a0A, a1B = a0A;
  if (p0 < p1) {
    int s = csr_src[p0];
    a0A = *(const f32x4*)(const void*)&csr_ea[(long)p0 * 8];
    a1A = *(const f32x4*)(const void*)&csr_ea[(long)p0 * 8 + 4];
    xA = *(const short4v*)(const void*)&xlb[(long)s * HC + cbase];
  }
  if (p0 + 1 < p1) {
    int s = csr_src[p0 + 1];
    a0B = *(const f32x4*)(const void*)&csr_ea[(long)(p0 + 1) * 8];
    a1B = *(const f32x4*)(const void*)&csr_ea[(long)(p0 + 1) * 8 + 4];
    xB = *(const short4v*)(const void*)&xlb[(long)s * HC + cbase];
  }
  int k = p0;
  for (; k + 2 <= p1; k += 2) {
    f32x4 e0 = a0A, e1 = a1A;
    short4v xc = xA;
    if (k + 2 < p1) {
      int s = csr_src[k + 2];
      a0A = *(const f32x4*)(const void*)&csr_ea[(long)(k + 2) * 8];
      a1A = *(const f32x4*)(const void*)&csr_ea[(long)(k + 2) * 8 + 4];
      xA = *(const short4v*)(const void*)&xlb[(long)s * HC + cbase];
    }
    eas0 += e0; eas1 += e1;
    edge_compute(bf4_to_f32(xc), e0, e1);

    e0 = a0B; e1 = a1B; xc = xB;
    if (k + 3 < p1) {
      int s = csr_src[k + 3];
      a0B = *(const f32x4*)(const void*)&csr_ea[(long)(k + 3) * 8];
      a1B = *(const f32x4*)(const void*)&csr_ea[(long)(k + 3) * 8 + 4];
      xB = *(const short4v*)(const void*)&xlb[(long)s * HC + cbase];
    }
    eas0 += e0; eas1 += e1;
    edge_compute(bf4_to_f32(xc), e0, e1);
  }
  if (k < p1) {           // odd tail lives in slot A
    eas0 += a0A; eas1 += a1A;
    edge_compute(bf4_to_f32(xA), a0A, a1A);
  }
  // self loop with mean edge_attr
  int cnt = p1 - p0;
  f32x4 xls_self = bf4_to_f32(*(const short4v*)(const void*)&xlb[(long)node * HC + cbase]);
  float invd = 1.f / (float)(cnt > 1 ? cnt : 1);
  edge_compute(xls_self, eas0 * invd, eas1 * invd);

  float invs = 1.f / rsum;
  short4v pk;
#pragma unroll
  for (int r = 0; r < 4; ++r) {
    float v = fmaxf(acc[r] * invs + biasv[r], 0.f);
    __hip_bfloat16 hv = __float2bfloat16(v);
    pk[r] = *(short*)&hv;
  }
  *(short4v*)&out[(long)node * HC + cbase] = pk;
}

extern "C" void kernel_launch(void* const* d_in, const int* in_sizes, int n_in,
                              void* d_out, int out_size, void* d_ws, size_t ws_size,
                              hipStream_t stream)
{
  const float* x          = (const float*)d_in[0];
  const int*   edge_index = (const int*)d_in[1];
  const float* edge_attr  = (const float*)d_in[2];
  const float* fp         = (const float*)d_in[4];
  const float* desc       = (const float*)d_in[5];
  const float *c1_Wl = (const float*)d_in[6],  *c1_bl = (const float*)d_in[7],
              *c1_Wr = (const float*)d_in[8],  *c1_br = (const float*)d_in[9],
              *c1_We = (const float*)d_in[10], *c1_att = (const float*)d_in[11],
              *c1_bias = (const float*)d_in[12];
  const float *c2_Wl = (const float*)d_in[13], *c2_bl = (const float*)d_in[14],
              *c2_Wr = (const float*)d_in[15], *c2_br = (const float*)d_in[16],
              *c2_We = (const float*)d_in[17], *c2_att = (const float*)d_in[18],
              *c2_bias = (const float*)d_in[19];
  const float *gW = (const float*)d_in[20], *gb = (const float*)d_in[21],
              *g_gn = (const float*)d_in[22], *g_bt = (const float*)d_in[23];
  const float *fW = (const float*)d_in[24], *fb = (const float*)d_in[25],
              *f_gn = (const float*)d_in[26], *f_bt = (const float*)d_in[27];
  const float *dW = (const float*)d_in[28], *db = (const float*)d_in[29],
              *d_gn = (const float*)d_in[30], *d_bt = (const float*)d_in[31];
  const float *k1W = (const float*)d_in[32], *k1b = (const float*)d_in[33],
              *k1_gn = (const float*)d_in[34], *k1_bt = (const float*)d_in[35];
  const float *k2W = (const float*)d_in[36], *k2b = (const float*)d_in[37],
              *k2_gn = (const float*)d_in[38], *k2_bt = (const float*)d_in[39];
  const float *k3W = (const float*)d_in[40], *k3b = (const float*)d_in[41];

  const int N = in_sizes[0] / 32;       // 32768
  const int E = in_sizes[1] / 2;        // 262144
  const int G = in_sizes[4] / 2048;     // 1024
  const int FIN = 32, FPIN = 2048;
  const int DIN = in_sizes[5] / G;      // 200

  char* ws = (char*)d_ws;
  size_t off = 0;
  auto alloc = [&](size_t bytes) {
    void* p = ws + off;
    off = (off + bytes + 255) & ~(size_t)255;
    return p;
  };
  __hip_bfloat16* xlb    = (__hip_bfloat16*)alloc((size_t)N * HC * 2);  // 16 MB
  __hip_bfloat16* xrb    = (__hip_bfloat16*)alloc((size_t)N * HC * 2);  // 16 MB
  __hip_bfloat16* hb1    = (__hip_bfloat16*)alloc((size_t)N * HC * 2);  // 16 MB
  __hip_bfloat16* hb2    = (__hip_bfloat16*)alloc((size_t)N * HC * 2);  // 16 MB
  __hip_bfloat16* xbf    = (__hip_bfloat16*)alloc((size_t)N * FIN * 2);
  __hip_bfloat16* fpbf   = (__hip_bfloat16*)alloc((size_t)G * FPIN * 2); // 4 MB
  __hip_bfloat16* wt1    = (__hip_bfloat16*)alloc((size_t)512 * FIN * 2);
  __hip_bfloat16* wt2    = (__hip_bfloat16*)alloc((size_t)512 * HC * 2);
  __hip_bfloat16* fwt    = (__hip_bfloat16*)alloc((size_t)256 * FPIN * 2); // 1 MB
  __hip_bfloat16* descbf = (__hip_bfloat16*)alloc((size_t)G * 224 * 2);
  __hip_bfloat16* dwt    = (__hip_bfloat16*)alloc((size_t)64 * 224 * 2);
  __hip_bfloat16* zbuf   = (__hip_bfloat16*)alloc((size_t)G * 384 * 2);
  int*   deg     = (int*)alloc((size_t)N * 4);
  int*   csr_ptr = (int*)alloc((size_t)(N + 1) * 4);
  int*   cursor  = (int*)alloc((size_t)N * 4);
  int*   csr_src = (int*)alloc((size_t)E * 4);
  float* csr_ea  = (float*)alloc((size_t)E * 8 * 4);                  // 8 MB
  (void)ws_size;

  const int* srcp = edge_index;
  const int* dstp = edge_index + E;

  hipMemsetAsync(deg, 0, (size_t)N * 4, stream);

  // prep: conversions + GAT-weight transposes + padded desc + degree count
  {
    long total = (long)N * FIN + (long)G * FPIN + 512 * 32 + 512 * 256 +
                 (long)G * 224 + 64 * 224 + E;
    prep_kernel<<<(int)((total + 255) / 256), 256, 0, stream>>>(
        x, fp, c1_Wl, c1_Wr, c2_Wl, c2_Wr, desc, dW, dstp, deg,
        xbf, fpbf, wt1, wt2, descbf, dwt, N, G, E, DIN);
  }
  transpose_fwt_kernel<<<dim3(2048 / 64, 256 / 64), 256, 0, stream>>>(fW, fwt);
  scan_kernel<<<1, 1024, 0, stream>>>(deg, csr_ptr, cursor, N);
  fill_kernel<<<(E + 255) / 256, 256, 0, stream>>>(srcp, dstp, edge_attr, cursor,
                                                   csr_src, csr_ea, E);

  // fp branch (bf16 MFMA) -> zbuf[:,64:320]
  gemm_rb_kernel<<<dim3(G / 64, 4), 256, 0, stream>>>(fpbf, fwt, fb, f_gn, f_bt,
                                                      zbuf, G, FPIN, 384, 64);
  // desc branch (bf16 MFMA, K padded to 224) -> zbuf[:,320:384]
  gemm_rb_kernel<<<dim3(G / 64, 1), 256, 0, stream>>>(descbf, dwt, db, d_gn, d_bt,
                                                      zbuf, G, 224, 384, 320);

  // layer 1
  gemm_mfma_kernel<<<dim3(N / 128, 4), 256, 0, stream>>>(xbf, wt1, c1_bl, c1_br, xlb, xrb, N, FIN);
  gat_kernel<<<N / 2, 128, 0, stream>>>(xlb, xrb, csr_ea, csr_src, csr_ptr,
                                        c1_We, c1_att, c1_bias, hb1, N);
  // layer 2
  gemm_mfma_kernel<<<dim3(N / 128, 4), 256, 0, stream>>>(hb1, wt2, c2_bl, c2_br, xlb, xrb, N, HC);
  gat_kernel<<<N / 2, 128, 0, stream>>>(xlb, xrb, csr_ea, csr_src, csr_ptr,
                                        c2_We, c2_att, c2_bias, hb2, N);

  // fused pool + g branch -> zbuf[:,0:64]
  poolg_kernel<<<G, 256, 0, stream>>>(hb2, gW, gb, g_gn, g_bt, zbuf, N / G);

  // fused k1+k2+k3 head
  head_kernel<<<G / 8, 256, 0, stream>>>(zbuf, k1W, k1b, k1_gn, k1_bt,
                                         k2W, k2b, k2_gn, k2_bt, k3W, k3b,
                                         (float*)d_out);
}

// Round 11
// 517.863 us; speedup vs baseline: 1.1144x; 1.1144x over previous
//
#include <hip/hip_runtime.h>
#include <hip/hip_bf16.h>
#include <math.h>

#define NHEAD 4
#define HC 256

typedef short short8 __attribute__((ext_vector_type(8)));
typedef short short4v __attribute__((ext_vector_type(4)));
typedef float f32x4 __attribute__((ext_vector_type(4)));

__device__ inline f32x4 bf4_to_f32(short4v v)
{
  f32x4 r;
#pragma unroll
  for (int i = 0; i < 4; ++i)
    r[i] = __uint_as_float(((unsigned)(unsigned short)v[i]) << 16);
  return r;
}

__device__ inline float bf_to_f32(unsigned short u)
{
  return __uint_as_float(((unsigned)u) << 16);
}

// ------- one fused prep kernel: fp32->bf16 conversions, weight transposes,
// desc/dW zero-padded to K=224, k1W^T, and the degree count -------
__global__ void prep_kernel(
    const float* __restrict__ x, const float* __restrict__ fp,
    const float* __restrict__ c1Wl, const float* __restrict__ c1Wr,
    const float* __restrict__ c2Wl, const float* __restrict__ c2Wr,
    const float* __restrict__ desc, const float* __restrict__ dW,
    const float* __restrict__ k1W,
    const int* __restrict__ dst, int* __restrict__ deg,
    __hip_bfloat16* __restrict__ xbf, __hip_bfloat16* __restrict__ fpbf,
    __hip_bfloat16* __restrict__ wt1, __hip_bfloat16* __restrict__ wt2,
    __hip_bfloat16* __restrict__ descbf, __hip_bfloat16* __restrict__ dwt,
    __hip_bfloat16* __restrict__ k1wt,
    int N, int G, int E, int DIN)
{
  const int n0 = N * 32, n1 = G * 2048, n2 = 512 * 32, n3 = 512 * 256;
  const int n4 = G * 224, n5 = 64 * 224, n6 = 192 * 384;
  int idx = blockIdx.x * 256 + threadIdx.x;
  if (idx < n0) { xbf[idx] = __float2bfloat16(x[idx]); return; }
  idx -= n0;
  if (idx < n1) { fpbf[idx] = __float2bfloat16(fp[idx]); return; }
  idx -= n1;
  if (idx < n2) {
    int n = idx / 32, k = idx - n * 32;
    float v = (n < 256) ? c1Wl[k * 256 + n] : c1Wr[k * 256 + (n - 256)];
    wt1[idx] = __float2bfloat16(v); return;
  }
  idx -= n2;
  if (idx < n3) {
    int n = idx / 256, k = idx - n * 256;
    float v = (n < 256) ? c2Wl[k * 256 + n] : c2Wr[k * 256 + (n - 256)];
    wt2[idx] = __float2bfloat16(v); return;
  }
  idx -= n3;
  if (idx < n4) {
    int row = idx / 224, kp = idx - row * 224;
    float v = (kp < DIN) ? desc[(long)row * DIN + kp] : 0.f;
    descbf[idx] = __float2bfloat16(v); return;
  }
  idx -= n4;
  if (idx < n5) {
    int n = idx / 224, kp = idx - n * 224;
    float v = (kp < DIN) ? dW[kp * 64 + n] : 0.f;
    dwt[idx] = __float2bfloat16(v); return;
  }
  idx -= n5;
  if (idx < n6) {
    int n = idx / 384, k = idx - n * 384;
    k1wt[idx] = __float2bfloat16(k1W[k * 192 + n]); return;
  }
  idx -= n6;
  if (idx < E) atomicAdd(&deg[dst[idx]], 1);
}

// ------- LDS-tiled transpose: fW[2048][256] f32 -> fwt[256][2048] bf16 -------
__global__ __launch_bounds__(256) void transpose_fwt_kernel(
    const float* __restrict__ fW, __hip_bfloat16* __restrict__ fwt)
{
  __shared__ float tile[64][65];
  int bk = blockIdx.x * 64, bn = blockIdx.y * 64;
  int tx = threadIdx.x & 63, ty = threadIdx.x >> 6;
#pragma unroll
  for (int j = 0; j < 16; ++j) {
    int kl = ty + j * 4;
    tile[kl][tx] = fW[(long)(bk + kl) * 256 + bn + tx];
  }
  __syncthreads();
#pragma unroll
  for (int j = 0; j < 16; ++j) {
    int nl = ty + j * 4;
    fwt[(long)(bn + nl) * 2048 + bk + tx] = __float2bfloat16(tile[tx][nl]);
  }
}

// ------- bf16 MFMA GEMM: [xl|xr] = A[M][K] @ W[K][512] + bias -> bf16 tables
// Tile 128(M) x 128(N); grid (M/128, 4). Halves A re-fetch vs 64-col tiles.
__global__ __launch_bounds__(256) void gemm_mfma_kernel(
    const __hip_bfloat16* __restrict__ A, const __hip_bfloat16* __restrict__ BT,
    const float* __restrict__ bl, const float* __restrict__ br,
    __hip_bfloat16* __restrict__ XL, __hip_bfloat16* __restrict__ XR, int M, int K)
{
  __shared__ short As[128 * 40];
  __shared__ short Bs[128 * 40];
  int bm = blockIdx.x * 128, bn = blockIdx.y * 128;
  int t = threadIdx.x;
  int w = t >> 6, l = t & 63;
  int quad = l >> 4, l16 = l & 15;
  int srow = t >> 1, scol = (t & 1) * 16;

  f32x4 acc[2][8];
#pragma unroll
  for (int i = 0; i < 2; ++i)
#pragma unroll
    for (int j = 0; j < 8; ++j) acc[i][j] = (f32x4){0.f, 0.f, 0.f, 0.f};

  for (int k0 = 0; k0 < K; k0 += 32) {
    *(short8*)&As[srow * 40 + scol] =
        *(const short8*)(const void*)&A[(long)(bm + srow) * K + k0 + scol];
    *(short8*)&As[srow * 40 + scol + 8] =
        *(const short8*)(const void*)&A[(long)(bm + srow) * K + k0 + scol + 8];
    *(short8*)&Bs[srow * 40 + scol] =
        *(const short8*)(const void*)&BT[(long)(bn + srow) * K + k0 + scol];
    *(short8*)&Bs[srow * 40 + scol + 8] =
        *(const short8*)(const void*)&BT[(long)(bn + srow) * K + k0 + scol + 8];
    __syncthreads();
    short8 af[2], bf[8];
#pragma unroll
    for (int mt = 0; mt < 2; ++mt)
      af[mt] = *(short8*)&As[(w * 32 + mt * 16 + l16) * 40 + quad * 8];
#pragma unroll
    for (int nt = 0; nt < 8; ++nt)
      bf[nt] = *(short8*)&Bs[(nt * 16 + l16) * 40 + quad * 8];
#pragma unroll
    for (int mt = 0; mt < 2; ++mt)
#pragma unroll
      for (int nt = 0; nt < 8; ++nt)
        acc[mt][nt] = __builtin_amdgcn_mfma_f32_16x16x32_bf16(af[mt], bf[nt], acc[mt][nt], 0, 0, 0);
    __syncthreads();
  }
#pragma unroll
  for (int mt = 0; mt < 2; ++mt)
#pragma unroll
    for (int nt = 0; nt < 8; ++nt) {
      int col = bn + nt * 16 + l16;
      float b = (col < 256) ? bl[col] : br[col - 256];
#pragma unroll
      for (int r = 0; r < 4; ++r) {
        int row = bm + w * 32 + mt * 16 + quad * 4 + r;
        float v = acc[mt][nt][r] + b;
        if (col < 256)
          XL[(long)row * 256 + col] = __float2bfloat16(v);
        else
          XR[(long)row * 256 + (col - 256)] = __float2bfloat16(v);
      }
    }
}

// ------- bf16 MFMA GEMM + relu + bn epilogue; out bf16 (obf=1) or fp32 -------
// A[M][K] bf16, BT[N][K] bf16 n-major. Tile 64x64, grid (M/64, N/64).
__global__ __launch_bounds__(256) void gemm_rb_kernel(
    const __hip_bfloat16* __restrict__ A, const __hip_bfloat16* __restrict__ BT,
    const float* __restrict__ bias, const float* __restrict__ gamma,
    const float* __restrict__ beta, void* __restrict__ out,
    int M, int K, int ldc, int coloff, int obf)
{
  __shared__ short As[64 * 40];
  __shared__ short Bs[64 * 40];
  int bm = blockIdx.x * 64, bn = blockIdx.y * 64;
  int t = threadIdx.x;
  int w = t >> 6, l = t & 63;
  int quad = l >> 4, l16 = l & 15;
  int lrow = t >> 2, col8 = (t & 3) * 8;

  f32x4 acc[4];
#pragma unroll
  for (int nt = 0; nt < 4; ++nt) acc[nt] = (f32x4){0.f, 0.f, 0.f, 0.f};

  for (int k0 = 0; k0 < K; k0 += 32) {
    *(short8*)&As[lrow * 40 + col8] =
        *(const short8*)(const void*)&A[(long)(bm + lrow) * K + k0 + col8];
    *(short8*)&Bs[lrow * 40 + col8] =
        *(const short8*)(const void*)&BT[(long)(bn + lrow) * K + k0 + col8];
    __syncthreads();
    short8 af = *(short8*)&As[(w * 16 + l16) * 40 + quad * 8];
#pragma unroll
    for (int nt = 0; nt < 4; ++nt) {
      short8 bf = *(short8*)&Bs[(nt * 16 + l16) * 40 + quad * 8];
      acc[nt] = __builtin_amdgcn_mfma_f32_16x16x32_bf16(af, bf, acc[nt], 0, 0, 0);
    }
    __syncthreads();
  }
  const float inv = rsqrtf(1.f + 1e-5f);
#pragma unroll
  for (int nt = 0; nt < 4; ++nt) {
    int col = bn + nt * 16 + l16;
    float b = bias[col], gm = gamma[col] * inv, bt = beta[col];
#pragma unroll
    for (int r = 0; r < 4; ++r) {
      int row = bm + w * 16 + quad * 4 + r;
      float v = fmaxf(acc[nt][r] + b, 0.f) * gm + bt;
      if (obf)
        ((__hip_bfloat16*)out)[(long)row * ldc + coloff + col] = __float2bfloat16(v);
      else
        ((float*)out)[(long)row * ldc + coloff + col] = v;
    }
  }
}

// -------- fused pool + g branch: per-graph colmax (LDS) -> 64-col dense -----
__global__ __launch_bounds__(256) void poolg_kernel(
    const __hip_bfloat16* __restrict__ h, const float* __restrict__ gW,
    const float* __restrict__ gb, const float* __restrict__ g_gn,
    const float* __restrict__ g_bt, __hip_bfloat16* __restrict__ zbuf, int npg)
{
  __shared__ float smax[256];
  __shared__ float sred[256];
  int g = blockIdx.x, t = threadIdx.x;
  const __hip_bfloat16* base = h + (long)g * npg * HC + t;
  float m = -INFINITY;
#pragma unroll 4
  for (int i = 0; i < npg; ++i)
    m = fmaxf(m, bf_to_f32(*(const unsigned short*)&base[(long)i * HC]));
  smax[t] = m;
  __syncthreads();
  int j = t >> 2, part = t & 3;
  float sum = 0.f;
#pragma unroll 4
  for (int k = part * 64; k < part * 64 + 64; ++k)
    sum = fmaf(smax[k], gW[k * 64 + j], sum);
  sred[t] = sum;
  __syncthreads();
  if (t < 64) {
    float v = sred[t * 4] + sred[t * 4 + 1] + sred[t * 4 + 2] + sred[t * 4 + 3];
    const float inv = rsqrtf(1.f + 1e-5f);
    v = fmaxf(v + gb[t], 0.f) * (g_gn[t] * inv) + g_bt[t];
    zbuf[(long)g * 384 + t] = __float2bfloat16(v);
  }
}

// -------- fused k2+k3 head: z1(fp32)[16 rows] -> d_out --------
// k1 stays a separate MFMA GEMM: fusing it here (R10) collapsed its 75M-FMA
// parallelism onto 128 blocks -> 130 us. Keep head scalar work k2+k3 only.
__global__ __launch_bounds__(256) void head23_kernel(
    const float* __restrict__ z1, const float* __restrict__ k2W,
    const float* __restrict__ k2b, const float* __restrict__ k2_gn,
    const float* __restrict__ k2_bt, const float* __restrict__ k3W,
    const float* __restrict__ k3b, float* __restrict__ out)
{
  __shared__ float s1[16 * 192];
  __shared__ float s2[16 * 96];
  int b = blockIdx.x, t = threadIdx.x;
  for (int i = t; i < 16 * 192; i += 256) s1[i] = z1[(long)b * 16 * 192 + i];
  __syncthreads();
  const float inv = rsqrtf(1.f + 1e-5f);
#pragma unroll
  for (int j = 0; j < 6; ++j) {
    int idx = j * 256 + t;
    int row = idx / 96, col = idx - row * 96;
    float acc = 0.f;
#pragma unroll 4
    for (int k = 0; k < 192; ++k) acc = fmaf(s1[row * 192 + k], k2W[k * 96 + col], acc);
    acc = fmaxf(acc + k2b[col], 0.f);
    s2[idx] = acc * (k2_gn[col] * inv) + k2_bt[col];
  }
  __syncthreads();
  if (t < 192) {
    int row = t / 12, col = t - row * 12;
    float acc = 0.f;
#pragma unroll 4
    for (int k = 0; k < 96; ++k) acc = fmaf(s2[row * 96 + k], k3W[k * 12 + col], acc);
    out[(long)(b * 16 + row) * 12 + col] = acc + k3b[col];
  }
}

// ---------------- CSR build ----------------
__global__ __launch_bounds__(1024) void scan_kernel(
    const int* __restrict__ deg, int* __restrict__ ptr, int* __restrict__ cursor, int N)
{
  __shared__ int sums[1024];
  int t = threadIdx.x;
  int base = t * 32;
  int local[32];
  int s = 0;
#pragma unroll
  for (int i = 0; i < 32; ++i) {
    int v = (base + i < N) ? deg[base + i] : 0;
    local[i] = v; s += v;
  }
  sums[t] = s;
  __syncthreads();
  for (int off = 1; off < 1024; off <<= 1) {
    int v = (t >= off) ? sums[t - off] : 0;
    __syncthreads();
    sums[t] += v;
    __syncthreads();
  }
  int excl = sums[t] - s;
  for (int i = 0; i < 32; ++i) {
    if (base + i < N) { ptr[base + i] = excl; cursor[base + i] = excl; excl += local[i]; }
  }
  if (t == 1023) ptr[N] = sums[1023];
}

// scatter src id AND edge_attr into CSR order
__global__ void fill_kernel(const int* __restrict__ src, const int* __restrict__ dst,
                            const float* __restrict__ ea, int* __restrict__ cursor,
                            int* __restrict__ csr_src, float* __restrict__ csr_ea, int E)
{
  int e = blockIdx.x * blockDim.x + threadIdx.x;
  if (e < E) {
    int pos = atomicAdd(&cursor[dst[e]], 1);
    csr_src[pos] = src[e];
    f32x4 a0 = *(const f32x4*)(const void*)&ea[(long)e * 8];
    f32x4 a1 = *(const f32x4*)(const void*)&ea[(long)e * 8 + 4];
    *(f32x4*)&csr_ea[(long)pos * 8] = a0;
    *(f32x4*)&csr_ea[(long)pos * 8 + 4] = a1;
  }
}

// ---------------- GATv2 aggregation ----------------
// lane = head*16 + quad; lane owns 4 channels of one head; 2 nodes / 128-thr
// block. NO min-waves launch_bounds (R8: forcing 8 waves/EU -> VGPR 32 ->
// scratch spills -> 2.4 GB traffic, 8x slower). Kernel needs ~64 VGPR.
__global__ __launch_bounds__(128) void gat_kernel(
    const __hip_bfloat16* __restrict__ xlb, const __hip_bfloat16* __restrict__ xrb,
    const float* __restrict__ csr_ea, const int* __restrict__ csr_src,
    const int* __restrict__ csr_ptr,
    const float* __restrict__ We, const float* __restrict__ att,
    const float* __restrict__ bias, __hip_bfloat16* __restrict__ out, int N)
{
  int lane = threadIdx.x & 63;
  int node = blockIdx.x * 2 + (threadIdx.x >> 6);
  if (node >= N) return;
  int cbase = (lane >> 4) * 64 + (lane & 15) * 4;  // channel offset in [0,256)

  f32x4 attv = *(const f32x4*)(const void*)&att[cbase];
  f32x4 xriv = bf4_to_f32(*(const short4v*)(const void*)&xrb[(long)node * HC + cbase]);
  f32x4 biasv = *(const f32x4*)(const void*)&bias[cbase];
  f32x4 WeR[8];
#pragma unroll
  for (int d = 0; d < 8; ++d)
    WeR[d] = *(const f32x4*)(const void*)&We[d * HC + cbase];

  float rsum = 0.f;
  f32x4 acc = (f32x4){0.f, 0.f, 0.f, 0.f};
  f32x4 eas0 = (f32x4){0.f, 0.f, 0.f, 0.f};
  f32x4 eas1 = (f32x4){0.f, 0.f, 0.f, 0.f};

  int p0 = csr_ptr[node], p1 = csr_ptr[node + 1];

  auto edge_compute = [&](f32x4 xls, f32x4 ea0, f32x4 ea1) {
    f32x4 mv = xriv + xls;
#pragma unroll
    for (int d = 0; d < 4; ++d) mv += WeR[d] * ea0[d];
#pragma unroll
    for (int d = 0; d < 4; ++d) mv += WeR[d + 4] * ea1[d];
    float t = 0.f;
#pragma unroll
    for (int r = 0; r < 4; ++r) {
      float m = mv[r];
      m = (m > 0.f) ? m : 0.2f * m;
      t = fmaf(m, attv[r], t);
    }
    t += __shfl_xor(t, 1, 64);
    t += __shfl_xor(t, 2, 64);
    t += __shfl_xor(t, 4, 64);
    t += __shfl_xor(t, 8, 64);
    float p = __expf(t);
    rsum += p;
    acc += p * xls;
  };

  // 2-deep prefetch, named slots A/B (runtime-indexed arrays kill codegen)
  short4v xA = (short4v){0, 0, 0, 0}, xB = (short4v){0, 0, 0, 0};
  f32x4 a0A = (f32x4){0.f, 0.f, 0.f, 0.f}, a1A = a0A, a0B = a0A, a1B = a0A;
  if (p0 < p1) {
    int s = csr_src[p0];
    a0A = *(const f32x4*)(const void*)&csr_ea[(long)p0 * 8];
    a1A = *(const f32x4*)(const void*)&csr_ea[(long)p0 * 8 + 4];
    xA = *(const short4v*)(const void*)&xlb[(long)s * HC + cbase];
  }
  if (p0 + 1 < p1) {
    int s = csr_src[p0 + 1];
    a0B = *(const f32x4*)(const void*)&csr_ea[(long)(p0 + 1) * 8];
    a1B = *(const f32x4*)(const void*)&csr_ea[(long)(p0 + 1) * 8 + 4];
    xB = *(const short4v*)(const void*)&xlb[(long)s * HC + cbase];
  }
  int k = p0;
  for (; k + 2 <= p1; k += 2) {
    f32x4 e0 = a0A, e1 = a1A;
    short4v xc = xA;
    if (k + 2 < p1) {
      int s = csr_src[k + 2];
      a0A = *(const f32x4*)(const void*)&csr_ea[(long)(k + 2) * 8];
      a1A = *(const f32x4*)(const void*)&csr_ea[(long)(k + 2) * 8 + 4];
      xA = *(const short4v*)(const void*)&xlb[(long)s * HC + cbase];
    }
    eas0 += e0; eas1 += e1;
    edge_compute(bf4_to_f32(xc), e0, e1);

    e0 = a0B; e1 = a1B; xc = xB;
    if (k + 3 < p1) {
      int s = csr_src[k + 3];
      a0B = *(const f32x4*)(const void*)&csr_ea[(long)(k + 3) * 8];
      a1B = *(const f32x4*)(const void*)&csr_ea[(long)(k + 3) * 8 + 4];
      xB = *(const short4v*)(const void*)&xlb[(long)s * HC + cbase];
    }
    eas0 += e0; eas1 += e1;
    edge_compute(bf4_to_f32(xc), e0, e1);
  }
  if (k < p1) {           // odd tail lives in slot A
    eas0 += a0A; eas1 += a1A;
    edge_compute(bf4_to_f32(xA), a0A, a1A);
  }
  // self loop with mean edge_attr
  int cnt = p1 - p0;
  f32x4 xls_self = bf4_to_f32(*(const short4v*)(const void*)&xlb[(long)node * HC + cbase]);
  float invd = 1.f / (float)(cnt > 1 ? cnt : 1);
  edge_compute(xls_self, eas0 * invd, eas1 * invd);

  float invs = 1.f / rsum;
  short4v pk;
#pragma unroll
  for (int r = 0; r < 4; ++r) {
    float v = fmaxf(acc[r] * invs + biasv[r], 0.f);
    __hip_bfloat16 hv = __float2bfloat16(v);
    pk[r] = *(short*)&hv;
  }
  *(short4v*)&out[(long)node * HC + cbase] = pk;
}

extern "C" void kernel_launch(void* const* d_in, const int* in_sizes, int n_in,
                              void* d_out, int out_size, void* d_ws, size_t ws_size,
                              hipStream_t stream)
{
  const float* x          = (const float*)d_in[0];
  const int*   edge_index = (const int*)d_in[1];
  const float* edge_attr  = (const float*)d_in[2];
  const float* fp         = (const float*)d_in[4];
  const float* desc       = (const float*)d_in[5];
  const float *c1_Wl = (const float*)d_in[6],  *c1_bl = (const float*)d_in[7],
              *c1_Wr = (const float*)d_in[8],  *c1_br = (const float*)d_in[9],
              *c1_We = (const float*)d_in[10], *c1_att = (const float*)d_in[11],
              *c1_bias = (const float*)d_in[12];
  const float *c2_Wl = (const float*)d_in[13], *c2_bl = (const float*)d_in[14],
              *c2_Wr = (const float*)d_in[15], *c2_br = (const float*)d_in[16],
              *c2_We = (const float*)d_in[17], *c2_att = (const float*)d_in[18],
              *c2_bias = (const float*)d_in[19];
  const float *gW = (const float*)d_in[20], *gb = (const float*)d_in[21],
              *g_gn = (const float*)d_in[22], *g_bt = (const float*)d_in[23];
  const float *fW = (const float*)d_in[24], *fb = (const float*)d_in[25],
              *f_gn = (const float*)d_in[26], *f_bt = (const float*)d_in[27];
  const float *dW = (const float*)d_in[28], *db = (const float*)d_in[29],
              *d_gn = (const float*)d_in[30], *d_bt = (const float*)d_in[31];
  const float *k1W = (const float*)d_in[32], *k1b = (const float*)d_in[33],
              *k1_gn = (const float*)d_in[34], *k1_bt = (const float*)d_in[35];
  const float *k2W = (const float*)d_in[36], *k2b = (const float*)d_in[37],
              *k2_gn = (const float*)d_in[38], *k2_bt = (const float*)d_in[39];
  const float *k3W = (const float*)d_in[40], *k3b = (const float*)d_in[41];

  const int N = in_sizes[0] / 32;       // 32768
  const int E = in_sizes[1] / 2;        // 262144
  const int G = in_sizes[4] / 2048;     // 1024
  const int FIN = 32, FPIN = 2048;
  const int DIN = in_sizes[5] / G;      // 200

  char* ws = (char*)d_ws;
  size_t off = 0;
  auto alloc = [&](size_t bytes) {
    void* p = ws + off;
    off = (off + bytes + 255) & ~(size_t)255;
    return p;
  };
  __hip_bfloat16* xlb    = (__hip_bfloat16*)alloc((size_t)N * HC * 2);  // 16 MB
  __hip_bfloat16* xrb    = (__hip_bfloat16*)alloc((size_t)N * HC * 2);  // 16 MB
  __hip_bfloat16* hb1    = (__hip_bfloat16*)alloc((size_t)N * HC * 2);  // 16 MB
  __hip_bfloat16* hb2    = (__hip_bfloat16*)alloc((size_t)N * HC * 2);  // 16 MB
  __hip_bfloat16* xbf    = (__hip_bfloat16*)alloc((size_t)N * FIN * 2);
  __hip_bfloat16* fpbf   = (__hip_bfloat16*)alloc((size_t)G * FPIN * 2); // 4 MB
  __hip_bfloat16* wt1    = (__hip_bfloat16*)alloc((size_t)512 * FIN * 2);
  __hip_bfloat16* wt2    = (__hip_bfloat16*)alloc((size_t)512 * HC * 2);
  __hip_bfloat16* fwt    = (__hip_bfloat16*)alloc((size_t)256 * FPIN * 2); // 1 MB
  __hip_bfloat16* descbf = (__hip_bfloat16*)alloc((size_t)G * 224 * 2);
  __hip_bfloat16* dwt    = (__hip_bfloat16*)alloc((size_t)64 * 224 * 2);
  __hip_bfloat16* k1wt   = (__hip_bfloat16*)alloc((size_t)192 * 384 * 2);
  __hip_bfloat16* zbuf   = (__hip_bfloat16*)alloc((size_t)G * 384 * 2);
  float* z1      = (float*)alloc((size_t)G * 192 * 4);
  int*   deg     = (int*)alloc((size_t)N * 4);
  int*   csr_ptr = (int*)alloc((size_t)(N + 1) * 4);
  int*   cursor  = (int*)alloc((size_t)N * 4);
  int*   csr_src = (int*)alloc((size_t)E * 4);
  float* csr_ea  = (float*)alloc((size_t)E * 8 * 4);                  // 8 MB
  (void)ws_size;

  const int* srcp = edge_index;
  const int* dstp = edge_index + E;

  hipMemsetAsync(deg, 0, (size_t)N * 4, stream);

  // prep: conversions + weight transposes + padded desc + k1W^T + degree count
  {
    long total = (long)N * FIN + (long)G * FPIN + 512 * 32 + 512 * 256 +
                 (long)G * 224 + 64 * 224 + 192 * 384 + E;
    prep_kernel<<<(int)((total + 255) / 256), 256, 0, stream>>>(
        x, fp, c1_Wl, c1_Wr, c2_Wl, c2_Wr, desc, dW, k1W, dstp, deg,
        xbf, fpbf, wt1, wt2, descbf, dwt, k1wt, N, G, E, DIN);
  }
  transpose_fwt_kernel<<<dim3(2048 / 64, 256 / 64), 256, 0, stream>>>(fW, fwt);
  scan_kernel<<<1, 1024, 0, stream>>>(deg, csr_ptr, cursor, N);
  fill_kernel<<<(E + 255) / 256, 256, 0, stream>>>(srcp, dstp, edge_attr, cursor,
                                                   csr_src, csr_ea, E);

  // fp branch (bf16 MFMA) -> zbuf[:,64:320]
  gemm_rb_kernel<<<dim3(G / 64, 4), 256, 0, stream>>>(fpbf, fwt, fb, f_gn, f_bt,
                                                      zbuf, G, FPIN, 384, 64, 1);
  // desc branch (bf16 MFMA, K padded to 224) -> zbuf[:,320:384]
  gemm_rb_kernel<<<dim3(G / 64, 1), 256, 0, stream>>>(descbf, dwt, db, d_gn, d_bt,
                                                      zbuf, G, 224, 384, 320, 1);

  // layer 1
  gemm_mfma_kernel<<<dim3(N / 128, 4), 256, 0, stream>>>(xbf, wt1, c1_bl, c1_br, xlb, xrb, N, FIN);
  gat_kernel<<<N / 2, 128, 0, stream>>>(xlb, xrb, csr_ea, csr_src, csr_ptr,
                                        c1_We, c1_att, c1_bias, hb1, N);
  // layer 2
  gemm_mfma_kernel<<<dim3(N / 128, 4), 256, 0, stream>>>(hb1, wt2, c2_bl, c2_br, xlb, xrb, N, HC);
  gat_kernel<<<N / 2, 128, 0, stream>>>(xlb, xrb, csr_ea, csr_src, csr_ptr,
                                        c2_We, c2_att, c2_bias, hb2, N);

  // fused pool + g branch -> zbuf[:,0:64]
  poolg_kernel<<<G, 256, 0, stream>>>(hb2, gW, gb, g_gn, g_bt, zbuf, N / G);

  // k1 (bf16 MFMA) -> z1 fp32
  gemm_rb_kernel<<<dim3(G / 64, 3), 256, 0, stream>>>(zbuf, k1wt, k1b, k1_gn, k1_bt,
                                                      z1, G, 384, 192, 0, 0);
  // k2+k3 head
  head23_kernel<<<G / 16, 256, 0, stream>>>(z1, k2W, k2b, k2_gn, k2_bt, k3W, k3b,
                                            (float*)d_out);
}

// Round 12
// 499.778 us; speedup vs baseline: 1.1547x; 1.0362x over previous
//
#include <hip/hip_runtime.h>
#include <hip/hip_bf16.h>
#include <math.h>

#define NHEAD 4
#define HC 256

typedef short short8 __attribute__((ext_vector_type(8)));
typedef short short4v __attribute__((ext_vector_type(4)));
typedef float f32x4 __attribute__((ext_vector_type(4)));

__device__ inline f32x4 bf4_to_f32(short4v v)
{
  f32x4 r;
#pragma unroll
  for (int i = 0; i < 4; ++i)
    r[i] = __uint_as_float(((unsigned)(unsigned short)v[i]) << 16);
  return r;
}

__device__ inline float bf_to_f32(unsigned short u)
{
  return __uint_as_float(((unsigned)u) << 16);
}

// ------- one fused prep kernel: fp32->bf16 conversions, weight transposes,
// desc/dW zero-padded to K=224, k1W^T, and the degree count -------
__global__ void prep_kernel(
    const float* __restrict__ x, const float* __restrict__ fp,
    const float* __restrict__ c1Wl, const float* __restrict__ c1Wr,
    const float* __restrict__ c2Wl, const float* __restrict__ c2Wr,
    const float* __restrict__ desc, const float* __restrict__ dW,
    const float* __restrict__ k1W,
    const int* __restrict__ dst, int* __restrict__ deg,
    __hip_bfloat16* __restrict__ xbf, __hip_bfloat16* __restrict__ fpbf,
    __hip_bfloat16* __restrict__ wt1, __hip_bfloat16* __restrict__ wt2,
    __hip_bfloat16* __restrict__ descbf, __hip_bfloat16* __restrict__ dwt,
    __hip_bfloat16* __restrict__ k1wt,
    int N, int G, int E, int DIN)
{
  const int n0 = N * 32, n1 = G * 2048, n2 = 512 * 32, n3 = 512 * 256;
  const int n4 = G * 224, n5 = 64 * 224, n6 = 192 * 384;
  int idx = blockIdx.x * 256 + threadIdx.x;
  if (idx < n0) { xbf[idx] = __float2bfloat16(x[idx]); return; }
  idx -= n0;
  if (idx < n1) { fpbf[idx] = __float2bfloat16(fp[idx]); return; }
  idx -= n1;
  if (idx < n2) {
    int n = idx / 32, k = idx - n * 32;
    float v = (n < 256) ? c1Wl[k * 256 + n] : c1Wr[k * 256 + (n - 256)];
    wt1[idx] = __float2bfloat16(v); return;
  }
  idx -= n2;
  if (idx < n3) {
    int n = idx / 256, k = idx - n * 256;
    float v = (n < 256) ? c2Wl[k * 256 + n] : c2Wr[k * 256 + (n - 256)];
    wt2[idx] = __float2bfloat16(v); return;
  }
  idx -= n3;
  if (idx < n4) {
    int row = idx / 224, kp = idx - row * 224;
    float v = (kp < DIN) ? desc[(long)row * DIN + kp] : 0.f;
    descbf[idx] = __float2bfloat16(v); return;
  }
  idx -= n4;
  if (idx < n5) {
    int n = idx / 224, kp = idx - n * 224;
    float v = (kp < DIN) ? dW[kp * 64 + n] : 0.f;
    dwt[idx] = __float2bfloat16(v); return;
  }
  idx -= n5;
  if (idx < n6) {
    int n = idx / 384, k = idx - n * 384;
    k1wt[idx] = __float2bfloat16(k1W[k * 192 + n]); return;
  }
  idx -= n6;
  if (idx < E) atomicAdd(&deg[dst[idx]], 1);
}

// ------- LDS-tiled transpose: fW[2048][256] f32 -> fwt[256][2048] bf16 -------
__global__ __launch_bounds__(256) void transpose_fwt_kernel(
    const float* __restrict__ fW, __hip_bfloat16* __restrict__ fwt)
{
  __shared__ float tile[64][65];
  int bk = blockIdx.x * 64, bn = blockIdx.y * 64;
  int tx = threadIdx.x & 63, ty = threadIdx.x >> 6;
#pragma unroll
  for (int j = 0; j < 16; ++j) {
    int kl = ty + j * 4;
    tile[kl][tx] = fW[(long)(bk + kl) * 256 + bn + tx];
  }
  __syncthreads();
#pragma unroll
  for (int j = 0; j < 16; ++j) {
    int nl = ty + j * 4;
    fwt[(long)(bn + nl) * 2048 + bk + tx] = __float2bfloat16(tile[tx][nl]);
  }
}

// ------- bf16 MFMA GEMM: [xl|xr] = A[M][K] @ W[K][512] + bias -> bf16 tables
// Tile 128(M) x 128(N); grid (M/128, 4).
__global__ __launch_bounds__(256) void gemm_mfma_kernel(
    const __hip_bfloat16* __restrict__ A, const __hip_bfloat16* __restrict__ BT,
    const float* __restrict__ bl, const float* __restrict__ br,
    __hip_bfloat16* __restrict__ XL, __hip_bfloat16* __restrict__ XR, int M, int K)
{
  __shared__ short As[128 * 40];
  __shared__ short Bs[128 * 40];
  int bm = blockIdx.x * 128, bn = blockIdx.y * 128;
  int t = threadIdx.x;
  int w = t >> 6, l = t & 63;
  int quad = l >> 4, l16 = l & 15;
  int srow = t >> 1, scol = (t & 1) * 16;

  f32x4 acc[2][8];
#pragma unroll
  for (int i = 0; i < 2; ++i)
#pragma unroll
    for (int j = 0; j < 8; ++j) acc[i][j] = (f32x4){0.f, 0.f, 0.f, 0.f};

  for (int k0 = 0; k0 < K; k0 += 32) {
    *(short8*)&As[srow * 40 + scol] =
        *(const short8*)(const void*)&A[(long)(bm + srow) * K + k0 + scol];
    *(short8*)&As[srow * 40 + scol + 8] =
        *(const short8*)(const void*)&A[(long)(bm + srow) * K + k0 + scol + 8];
    *(short8*)&Bs[srow * 40 + scol] =
        *(const short8*)(const void*)&BT[(long)(bn + srow) * K + k0 + scol];
    *(short8*)&Bs[srow * 40 + scol + 8] =
        *(const short8*)(const void*)&BT[(long)(bn + srow) * K + k0 + scol + 8];
    __syncthreads();
    short8 af[2], bf[8];
#pragma unroll
    for (int mt = 0; mt < 2; ++mt)
      af[mt] = *(short8*)&As[(w * 32 + mt * 16 + l16) * 40 + quad * 8];
#pragma unroll
    for (int nt = 0; nt < 8; ++nt)
      bf[nt] = *(short8*)&Bs[(nt * 16 + l16) * 40 + quad * 8];
#pragma unroll
    for (int mt = 0; mt < 2; ++mt)
#pragma unroll
      for (int nt = 0; nt < 8; ++nt)
        acc[mt][nt] = __builtin_amdgcn_mfma_f32_16x16x32_bf16(af[mt], bf[nt], acc[mt][nt], 0, 0, 0);
    __syncthreads();
  }
#pragma unroll
  for (int mt = 0; mt < 2; ++mt)
#pragma unroll
    for (int nt = 0; nt < 8; ++nt) {
      int col = bn + nt * 16 + l16;
      float b = (col < 256) ? bl[col] : br[col - 256];
#pragma unroll
      for (int r = 0; r < 4; ++r) {
        int row = bm + w * 32 + mt * 16 + quad * 4 + r;
        float v = acc[mt][nt][r] + b;
        if (col < 256)
          XL[(long)row * 256 + col] = __float2bfloat16(v);
        else
          XR[(long)row * 256 + (col - 256)] = __float2bfloat16(v);
      }
    }
}

// ------- bf16 MFMA GEMM + relu + bn epilogue; out bf16 (obf=1) or fp32 -------
__global__ __launch_bounds__(256) void gemm_rb_kernel(
    const __hip_bfloat16* __restrict__ A, const __hip_bfloat16* __restrict__ BT,
    const float* __restrict__ bias, const float* __restrict__ gamma,
    const float* __restrict__ beta, void* __restrict__ out,
    int M, int K, int ldc, int coloff, int obf)
{
  __shared__ short As[64 * 40];
  __shared__ short Bs[64 * 40];
  int bm = blockIdx.x * 64, bn = blockIdx.y * 64;
  int t = threadIdx.x;
  int w = t >> 6, l = t & 63;
  int quad = l >> 4, l16 = l & 15;
  int lrow = t >> 2, col8 = (t & 3) * 8;

  f32x4 acc[4];
#pragma unroll
  for (int nt = 0; nt < 4; ++nt) acc[nt] = (f32x4){0.f, 0.f, 0.f, 0.f};

  for (int k0 = 0; k0 < K; k0 += 32) {
    *(short8*)&As[lrow * 40 + col8] =
        *(const short8*)(const void*)&A[(long)(bm + lrow) * K + k0 + col8];
    *(short8*)&Bs[lrow * 40 + col8] =
        *(const short8*)(const void*)&BT[(long)(bn + lrow) * K + k0 + col8];
    __syncthreads();
    short8 af = *(short8*)&As[(w * 16 + l16) * 40 + quad * 8];
#pragma unroll
    for (int nt = 0; nt < 4; ++nt) {
      short8 bf = *(short8*)&Bs[(nt * 16 + l16) * 40 + quad * 8];
      acc[nt] = __builtin_amdgcn_mfma_f32_16x16x32_bf16(af, bf, acc[nt], 0, 0, 0);
    }
    __syncthreads();
  }
  const float inv = rsqrtf(1.f + 1e-5f);
#pragma unroll
  for (int nt = 0; nt < 4; ++nt) {
    int col = bn + nt * 16 + l16;
    float b = bias[col], gm = gamma[col] * inv, bt = beta[col];
#pragma unroll
    for (int r = 0; r < 4; ++r) {
      int row = bm + w * 16 + quad * 4 + r;
      float v = fmaxf(acc[nt][r] + b, 0.f) * gm + bt;
      if (obf)
        ((__hip_bfloat16*)out)[(long)row * ldc + coloff + col] = __float2bfloat16(v);
      else
        ((float*)out)[(long)row * ldc + coloff + col] = v;
    }
  }
}

// ------- split-K bf16 MFMA (fp branch): grid.z = split; partials -> P fp32 ---
__global__ __launch_bounds__(256) void gemm_skb_kernel(
    const __hip_bfloat16* __restrict__ A, const __hip_bfloat16* __restrict__ BT,
    float* __restrict__ P, int M, int N, int K, int Kc)
{
  __shared__ short As[64 * 40];
  __shared__ short Bs[64 * 40];
  int bm = blockIdx.x * 64, bn = blockIdx.y * 64;
  int s = blockIdx.z;
  int kb = s * Kc, ke = kb + Kc;
  int t = threadIdx.x;
  int w = t >> 6, l = t & 63;
  int quad = l >> 4, l16 = l & 15;
  int lrow = t >> 2, col8 = (t & 3) * 8;

  f32x4 acc[4];
#pragma unroll
  for (int nt = 0; nt < 4; ++nt) acc[nt] = (f32x4){0.f, 0.f, 0.f, 0.f};

  for (int k0 = kb; k0 < ke; k0 += 32) {
    *(short8*)&As[lrow * 40 + col8] =
        *(const short8*)(const void*)&A[(long)(bm + lrow) * K + k0 + col8];
    *(short8*)&Bs[lrow * 40 + col8] =
        *(const short8*)(const void*)&BT[(long)(bn + lrow) * K + k0 + col8];
    __syncthreads();
    short8 af = *(short8*)&As[(w * 16 + l16) * 40 + quad * 8];
#pragma unroll
    for (int nt = 0; nt < 4; ++nt) {
      short8 bf = *(short8*)&Bs[(nt * 16 + l16) * 40 + quad * 8];
      acc[nt] = __builtin_amdgcn_mfma_f32_16x16x32_bf16(af, bf, acc[nt], 0, 0, 0);
    }
    __syncthreads();
  }
#pragma unroll
  for (int nt = 0; nt < 4; ++nt) {
    int col = bn + nt * 16 + l16;
#pragma unroll
    for (int r = 0; r < 4; ++r) {
      int row = bm + w * 16 + quad * 4 + r;
      P[((long)s * M + row) * N + col] = acc[nt][r];
    }
  }
}

// epilogue for fp split-K: sum 4 partials + bias/relu/bn -> zbuf[:,64:320] bf16
__global__ __launch_bounds__(256) void fp_epilogue_kernel(
    const float* __restrict__ P, const float* __restrict__ bias,
    const float* __restrict__ gamma, const float* __restrict__ beta,
    __hip_bfloat16* __restrict__ zbuf, int M, int N, int S)
{
  int idx = blockIdx.x * 256 + threadIdx.x;
  if (idx >= M * N) return;
  int row = idx / N, col = idx - row * N;
  float v = 0.f;
  for (int s = 0; s < S; ++s) v += P[(long)s * M * N + idx];
  const float inv = rsqrtf(1.f + 1e-5f);
  v = fmaxf(v + bias[col], 0.f) * (gamma[col] * inv) + beta[col];
  zbuf[(long)row * 384 + 64 + col] = __float2bfloat16(v);
}

// -------- fused pool + g branch: per-graph colmax (LDS) -> 64-col dense -----
__global__ __launch_bounds__(256) void poolg_kernel(
    const __hip_bfloat16* __restrict__ h, const float* __restrict__ gW,
    const float* __restrict__ gb, const float* __restrict__ g_gn,
    const float* __restrict__ g_bt, __hip_bfloat16* __restrict__ zbuf, int npg)
{
  __shared__ float smax[256];
  __shared__ float sred[256];
  int g = blockIdx.x, t = threadIdx.x;
  const __hip_bfloat16* base = h + (long)g * npg * HC + t;
  float m = -INFINITY;
#pragma unroll 4
  for (int i = 0; i < npg; ++i)
    m = fmaxf(m, bf_to_f32(*(const unsigned short*)&base[(long)i * HC]));
  smax[t] = m;
  __syncthreads();
  int j = t >> 2, part = t & 3;
  float sum = 0.f;
#pragma unroll 4
  for (int k = part * 64; k < part * 64 + 64; ++k)
    sum = fmaf(smax[k], gW[k * 64 + j], sum);
  sred[t] = sum;
  __syncthreads();
  if (t < 64) {
    float v = sred[t * 4] + sred[t * 4 + 1] + sred[t * 4 + 2] + sred[t * 4 + 3];
    const float inv = rsqrtf(1.f + 1e-5f);
    v = fmaxf(v + gb[t], 0.f) * (g_gn[t] * inv) + g_bt[t];
    zbuf[(long)g * 384 + t] = __float2bfloat16(v);
  }
}

// -------- fused k2+k3 head: z1(fp32)[16 rows] -> d_out --------
__global__ __launch_bounds__(256) void head23_kernel(
    const float* __restrict__ z1, const float* __restrict__ k2W,
    const float* __restrict__ k2b, const float* __restrict__ k2_gn,
    const float* __restrict__ k2_bt, const float* __restrict__ k3W,
    const float* __restrict__ k3b, float* __restrict__ out)
{
  __shared__ float s1[16 * 192];
  __shared__ float s2[16 * 96];
  int b = blockIdx.x, t = threadIdx.x;
  for (int i = t; i < 16 * 192; i += 256) s1[i] = z1[(long)b * 16 * 192 + i];
  __syncthreads();
  const float inv = rsqrtf(1.f + 1e-5f);
#pragma unroll
  for (int j = 0; j < 6; ++j) {
    int idx = j * 256 + t;
    int row = idx / 96, col = idx - row * 96;
    float acc = 0.f;
#pragma unroll 4
    for (int k = 0; k < 192; ++k) acc = fmaf(s1[row * 192 + k], k2W[k * 96 + col], acc);
    acc = fmaxf(acc + k2b[col], 0.f);
    s2[idx] = acc * (k2_gn[col] * inv) + k2_bt[col];
  }
  __syncthreads();
  if (t < 192) {
    int row = t / 12, col = t - row * 12;
    float acc = 0.f;
#pragma unroll 4
    for (int k = 0; k < 96; ++k) acc = fmaf(s2[row * 96 + k], k3W[k * 12 + col], acc);
    out[(long)(b * 16 + row) * 12 + col] = acc + k3b[col];
  }
}

// ---------------- CSR build ----------------
__global__ __launch_bounds__(1024) void scan_kernel(
    const int* __restrict__ deg, int* __restrict__ ptr, int* __restrict__ cursor, int N)
{
  __shared__ int sums[1024];
  int t = threadIdx.x;
  int base = t * 32;
  int local[32];
  int s = 0;
#pragma unroll
  for (int i = 0; i < 32; ++i) {
    int v = (base + i < N) ? deg[base + i] : 0;
    local[i] = v; s += v;
  }
  sums[t] = s;
  __syncthreads();
  for (int off = 1; off < 1024; off <<= 1) {
    int v = (t >= off) ? sums[t - off] : 0;
    __syncthreads();
    sums[t] += v;
    __syncthreads();
  }
  int excl = sums[t] - s;
  for (int i = 0; i < 32; ++i) {
    if (base + i < N) { ptr[base + i] = excl; cursor[base + i] = excl; excl += local[i]; }
  }
  if (t == 1023) ptr[N] = sums[1023];
}

// scatter src id AND edge_attr into CSR order
__global__ void fill_kernel(const int* __restrict__ src, const int* __restrict__ dst,
                            const float* __restrict__ ea, int* __restrict__ cursor,
                            int* __restrict__ csr_src, float* __restrict__ csr_ea, int E)
{
  int e = blockIdx.x * blockDim.x + threadIdx.x;
  if (e < E) {
    int pos = atomicAdd(&cursor[dst[e]], 1);
    csr_src[pos] = src[e];
    f32x4 a0 = *(const f32x4*)(const void*)&ea[(long)e * 8];
    f32x4 a1 = *(const f32x4*)(const void*)&ea[(long)e * 8 + 4];
    *(f32x4*)&csr_ea[(long)pos * 8] = a0;
    *(f32x4*)&csr_ea[(long)pos * 8 + 4] = a1;
  }
}

// ---------------- GATv2 aggregation ----------------
// lane = head*16 + quad; lane owns 4 channels of one head; 2 nodes / 128-thr
// block. NO min-waves launch_bounds (R8 lesson: forcing VGPR down -> spills).
// Independent A/B accumulator pairs break the online-softmax dependency
// between the two unrolled edges -> 2x ILP in the hot loop (merge is exact:
// no max-rescaling, plain sums).
__global__ __launch_bounds__(128) void gat_kernel(
    const __hip_bfloat16* __restrict__ xlb, const __hip_bfloat16* __restrict__ xrb,
    const float* __restrict__ csr_ea, const int* __restrict__ csr_src,
    const int* __restrict__ csr_ptr,
    const float* __restrict__ We, const float* __restrict__ att,
    const float* __restrict__ bias, __hip_bfloat16* __restrict__ out, int N)
{
  int lane = threadIdx.x & 63;
  int node = blockIdx.x * 2 + (threadIdx.x >> 6);
  if (node >= N) return;
  int cbase = (lane >> 4) * 64 + (lane & 15) * 4;  // channel offset in [0,256)

  f32x4 attv = *(const f32x4*)(const void*)&att[cbase];
  f32x4 xriv = bf4_to_f32(*(const short4v*)(const void*)&xrb[(long)node * HC + cbase]);
  f32x4 WeR[8];
#pragma unroll
  for (int d = 0; d < 8; ++d)
    WeR[d] = *(const f32x4*)(const void*)&We[d * HC + cbase];

  float rsumA = 0.f, rsumB = 0.f;
  f32x4 accA = (f32x4){0.f, 0.f, 0.f, 0.f};
  f32x4 accB = (f32x4){0.f, 0.f, 0.f, 0.f};
  f32x4 eas0 = (f32x4){0.f, 0.f, 0.f, 0.f};
  f32x4 eas1 = (f32x4){0.f, 0.f, 0.f, 0.f};

  int p0 = csr_ptr[node], p1 = csr_ptr[node + 1];

  auto edge_compute = [&](f32x4 xls, f32x4 ea0, f32x4 ea1,
                          float& rsum, f32x4& acc) {
    f32x4 mv = xriv + xls;
#pragma unroll
    for (int d = 0; d < 4; ++d) mv += WeR[d] * ea0[d];
#pragma unroll
    for (int d = 0; d < 4; ++d) mv += WeR[d + 4] * ea1[d];
    float t = 0.f;
#pragma unroll
    for (int r = 0; r < 4; ++r) {
      float m = mv[r];
      m = (m > 0.f) ? m : 0.2f * m;
      t = fmaf(m, attv[r], t);
    }
    t += __shfl_xor(t, 1, 64);
    t += __shfl_xor(t, 2, 64);
    t += __shfl_xor(t, 4, 64);
    t += __shfl_xor(t, 8, 64);
    float p = __expf(t);
    rsum += p;
    acc += p * xls;
  };

  // 2-deep prefetch, named slots A/B (runtime-indexed arrays kill codegen)
  short4v xA = (short4v){0, 0, 0, 0}, xB = (short4v){0, 0, 0, 0};
  f32x4 a0A = (f32x4){0.f, 0.f, 0.f, 0.f}, a1A = a0A, a0B = a0A, a1B = a0A;
  if (p0 < p1) {
    int s = csr_src[p0];
    a0A = *(const f32x4*)(const void*)&csr_ea[(long)p0 * 8];
    a1A = *(const f32x4*)(const void*)&csr_ea[(long)p0 * 8 + 4];
    xA = *(const short4v*)(const void*)&xlb[(long)s * HC + cbase];
  }
  if (p0 + 1 < p1) {
    int s = csr_src[p0 + 1];
    a0B = *(const f32x4*)(const void*)&csr_ea[(long)(p0 + 1) * 8];
    a1B = *(const f32x4*)(const void*)&csr_ea[(long)(p0 + 1) * 8 + 4];
    xB = *(const short4v*)(const void*)&xlb[(long)s * HC + cbase];
  }
  int k = p0;
  for (; k + 2 <= p1; k += 2) {
    f32x4 e0a = a0A, e1a = a1A;
    short4v xca = xA;
    if (k + 2 < p1) {
      int s = csr_src[k + 2];
      a0A = *(const f32x4*)(const void*)&csr_ea[(long)(k + 2) * 8];
      a1A = *(const f32x4*)(const void*)&csr_ea[(long)(k + 2) * 8 + 4];
      xA = *(const short4v*)(const void*)&xlb[(long)s * HC + cbase];
    }
    f32x4 e0b = a0B, e1b = a1B;
    short4v xcb = xB;
    if (k + 3 < p1) {
      int s = csr_src[k + 3];
      a0B = *(const f32x4*)(const void*)&csr_ea[(long)(k + 3) * 8];
      a1B = *(const f32x4*)(const void*)&csr_ea[(long)(k + 3) * 8 + 4];
      xB = *(const short4v*)(const void*)&xlb[(long)s * HC + cbase];
    }
    eas0 += e0a + e0b;
    eas1 += e1a + e1b;
    // independent accumulator pairs: the two calls have no data dependency
    edge_compute(bf4_to_f32(xca), e0a, e1a, rsumA, accA);
    edge_compute(bf4_to_f32(xcb), e0b, e1b, rsumB, accB);
  }
  if (k < p1) {           // odd tail lives in slot A
    eas0 += a0A; eas1 += a1A;
    edge_compute(bf4_to_f32(xA), a0A, a1A, rsumA, accA);
  }
  // self loop with mean edge_attr
  int cnt = p1 - p0;
  f32x4 xls_self = bf4_to_f32(*(const short4v*)(const void*)&xlb[(long)node * HC + cbase]);
  float invd = 1.f / (float)(cnt > 1 ? cnt : 1);
  edge_compute(xls_self, eas0 * invd, eas1 * invd, rsumB, accB);

  float invs = 1.f / (rsumA + rsumB);
  f32x4 biasv = *(const f32x4*)(const void*)&bias[cbase];
  short4v pk;
#pragma unroll
  for (int r = 0; r < 4; ++r) {
    float v = fmaxf((accA[r] + accB[r]) * invs + biasv[r], 0.f);
    __hip_bfloat16 hv = __float2bfloat16(v);
    pk[r] = *(short*)&hv;
  }
  *(short4v*)&out[(long)node * HC + cbase] = pk;
}

extern "C" void kernel_launch(void* const* d_in, const int* in_sizes, int n_in,
                              void* d_out, int out_size, void* d_ws, size_t ws_size,
                              hipStream_t stream)
{
  const float* x          = (const float*)d_in[0];
  const int*   edge_index = (const int*)d_in[1];
  const float* edge_attr  = (const float*)d_in[2];
  const float* fp         = (const float*)d_in[4];
  const float* desc       = (const float*)d_in[5];
  const float *c1_Wl = (const float*)d_in[6],  *c1_bl = (const float*)d_in[7],
              *c1_Wr = (const float*)d_in[8],  *c1_br = (const float*)d_in[9],
              *c1_We = (const float*)d_in[10], *c1_att = (const float*)d_in[11],
              *c1_bias = (const float*)d_in[12];
  const float *c2_Wl = (const float*)d_in[13], *c2_bl = (const float*)d_in[14],
              *c2_Wr = (const float*)d_in[15], *c2_br = (const float*)d_in[16],
              *c2_We = (const float*)d_in[17], *c2_att = (const float*)d_in[18],
              *c2_bias = (const float*)d_in[19];
  const float *gW = (const float*)d_in[20], *gb = (const float*)d_in[21],
              *g_gn = (const float*)d_in[22], *g_bt = (const float*)d_in[23];
  const float *fW = (const float*)d_in[24], *fb = (const float*)d_in[25],
              *f_gn = (const float*)d_in[26], *f_bt = (const float*)d_in[27];
  const float *dW = (const float*)d_in[28], *db = (const float*)d_in[29],
              *d_gn = (const float*)d_in[30], *d_bt = (const float*)d_in[31];
  const float *k1W = (const float*)d_in[32], *k1b = (const float*)d_in[33],
              *k1_gn = (const float*)d_in[34], *k1_bt = (const float*)d_in[35];
  const float *k2W = (const float*)d_in[36], *k2b = (const float*)d_in[37],
              *k2_gn = (const float*)d_in[38], *k2_bt = (const float*)d_in[39];
  const float *k3W = (const float*)d_in[40], *k3b = (const float*)d_in[41];

  const int N = in_sizes[0] / 32;       // 32768
  const int E = in_sizes[1] / 2;        // 262144
  const int G = in_sizes[4] / 2048;     // 1024
  const int FIN = 32, FPIN = 2048;
  const int DIN = in_sizes[5] / G;      // 200

  char* ws = (char*)d_ws;
  size_t off = 0;
  auto alloc = [&](size_t bytes) {
    void* p = ws + off;
    off = (off + bytes + 255) & ~(size_t)255;
    return p;
  };
  __hip_bfloat16* xlb    = (__hip_bfloat16*)alloc((size_t)N * HC * 2);  // 16 MB
  __hip_bfloat16* xrb    = (__hip_bfloat16*)alloc((size_t)N * HC * 2);  // 16 MB
  __hip_bfloat16* hb1    = (__hip_bfloat16*)alloc((size_t)N * HC * 2);  // 16 MB
  __hip_bfloat16* hb2    = (__hip_bfloat16*)alloc((size_t)N * HC * 2);  // 16 MB
  __hip_bfloat16* xbf    = (__hip_bfloat16*)alloc((size_t)N * FIN * 2);
  __hip_bfloat16* fpbf   = (__hip_bfloat16*)alloc((size_t)G * FPIN * 2); // 4 MB
  __hip_bfloat16* wt1    = (__hip_bfloat16*)alloc((size_t)512 * FIN * 2);
  __hip_bfloat16* wt2    = (__hip_bfloat16*)alloc((size_t)512 * HC * 2);
  __hip_bfloat16* fwt    = (__hip_bfloat16*)alloc((size_t)256 * FPIN * 2); // 1 MB
  __hip_bfloat16* descbf = (__hip_bfloat16*)alloc((size_t)G * 224 * 2);
  __hip_bfloat16* dwt    = (__hip_bfloat16*)alloc((size_t)64 * 224 * 2);
  __hip_bfloat16* k1wt   = (__hip_bfloat16*)alloc((size_t)192 * 384 * 2);
  __hip_bfloat16* zbuf   = (__hip_bfloat16*)alloc((size_t)G * 384 * 2);
  float* z1      = (float*)alloc((size_t)G * 192 * 4);
  float* P_fp    = (float*)alloc((size_t)4 * G * 256 * 4);             // 4 MB
  int*   deg     = (int*)alloc((size_t)N * 4);
  int*   csr_ptr = (int*)alloc((size_t)(N + 1) * 4);
  int*   cursor  = (int*)alloc((size_t)N * 4);
  int*   csr_src = (int*)alloc((size_t)E * 4);
  float* csr_ea  = (float*)alloc((size_t)E * 8 * 4);                  // 8 MB
  (void)ws_size;

  const int* srcp = edge_index;
  const int* dstp = edge_index + E;

  hipMemsetAsync(deg, 0, (size_t)N * 4, stream);

  // prep: conversions + weight transposes + padded desc + k1W^T + degree count
  {
    long total = (long)N * FIN + (long)G * FPIN + 512 * 32 + 512 * 256 +
                 (long)G * 224 + 64 * 224 + 192 * 384 + E;
    prep_kernel<<<(int)((total + 255) / 256), 256, 0, stream>>>(
        x, fp, c1_Wl, c1_Wr, c2_Wl, c2_Wr, desc, dW, k1W, dstp, deg,
        xbf, fpbf, wt1, wt2, descbf, dwt, k1wt, N, G, E, DIN);
  }
  transpose_fwt_kernel<<<dim3(2048 / 64, 256 / 64), 256, 0, stream>>>(fW, fwt);
  scan_kernel<<<1, 1024, 0, stream>>>(deg, csr_ptr, cursor, N);
  fill_kernel<<<(E + 255) / 256, 256, 0, stream>>>(srcp, dstp, edge_attr, cursor,
                                                   csr_src, csr_ea, E);

  // fp branch: split-K MFMA (256 blocks) + epilogue -> zbuf[:,64:320]
  gemm_skb_kernel<<<dim3(G / 64, 4, 4), 256, 0, stream>>>(fpbf, fwt, P_fp,
                                                          G, 256, FPIN, FPIN / 4);
  fp_epilogue_kernel<<<(G * 256 + 255) / 256, 256, 0, stream>>>(P_fp, fb, f_gn, f_bt,
                                                                zbuf, G, 256, 4);
  // desc branch (bf16 MFMA, K padded to 224) -> zbuf[:,320:384]
  gemm_rb_kernel<<<dim3(G / 64, 1), 256, 0, stream>>>(descbf, dwt, db, d_gn, d_bt,
                                                      zbuf, G, 224, 384, 320, 1);

  // layer 1
  gemm_mfma_kernel<<<dim3(N / 128, 4), 256, 0, stream>>>(xbf, wt1, c1_bl, c1_br, xlb, xrb, N, FIN);
  gat_kernel<<<N / 2, 128, 0, stream>>>(xlb, xrb, csr_ea, csr_src, csr_ptr,
                                        c1_We, c1_att, c1_bias, hb1, N);
  // layer 2
  gemm_mfma_kernel<<<dim3(N / 128, 4), 256, 0, stream>>>(hb1, wt2, c2_bl, c2_br, xlb, xrb, N, HC);
  gat_kernel<<<N / 2, 128, 0, stream>>>(xlb, xrb, csr_ea, csr_src, csr_ptr,
                                        c2_We, c2_att, c2_bias, hb2, N);

  // fused pool + g branch -> zbuf[:,0:64]
  poolg_kernel<<<G, 256, 0, stream>>>(hb2, gW, gb, g_gn, g_bt, zbuf, N / G);

  // k1 (bf16 MFMA) -> z1 fp32
  gemm_rb_kernel<<<dim3(G / 64, 3), 256, 0, stream>>>(zbuf, k1wt, k1b, k1_gn, k1_bt,
                                                      z1, G, 384, 192, 0, 0);
  // k2+k3 head
  head23_kernel<<<G / 16, 256, 0, stream>>>(z1, k2W, k2b, k2_gn, k2_bt, k3W, k3b,
                                            (float*)d_out);
}

// Round 13
// 494.665 us; speedup vs baseline: 1.1666x; 1.0103x over previous
//
#include <hip/hip_runtime.h>
#include <hip/hip_bf16.h>
#include <math.h>

#define NHEAD 4
#define HC 256

typedef short short8 __attribute__((ext_vector_type(8)));
typedef short short4v __attribute__((ext_vector_type(4)));
typedef float f32x4 __attribute__((ext_vector_type(4)));

__device__ inline f32x4 bf4_to_f32(short4v v)
{
  f32x4 r;
#pragma unroll
  for (int i = 0; i < 4; ++i)
    r[i] = __uint_as_float(((unsigned)(unsigned short)v[i]) << 16);
  return r;
}

__device__ inline float bf_to_f32(unsigned short u)
{
  return __uint_as_float(((unsigned)u) << 16);
}

// DPP rotate-add within a row of 16 lanes (VALU-only, no LDS/swizzle wait).
// CTRL: 0x121=row_ror:1, 0x122=ror:2, 0x124=ror:4, 0x128=ror:8.
template <int CTRL>
__device__ inline float dpp_radd(float x)
{
  int yi = __builtin_amdgcn_update_dpp(0, __float_as_int(x), CTRL, 0xf, 0xf, true);
  return x + __int_as_float(yi);
}

// ------- one fused prep kernel: fp32->bf16 conversions, weight transposes,
// desc/dW zero-padded to K=224, k1W^T, and the degree count -------
__global__ void prep_kernel(
    const float* __restrict__ x, const float* __restrict__ fp,
    const float* __restrict__ c1Wl, const float* __restrict__ c1Wr,
    const float* __restrict__ c2Wl, const float* __restrict__ c2Wr,
    const float* __restrict__ desc, const float* __restrict__ dW,
    const float* __restrict__ k1W,
    const int* __restrict__ dst, int* __restrict__ deg,
    __hip_bfloat16* __restrict__ xbf, __hip_bfloat16* __restrict__ fpbf,
    __hip_bfloat16* __restrict__ wt1, __hip_bfloat16* __restrict__ wt2,
    __hip_bfloat16* __restrict__ descbf, __hip_bfloat16* __restrict__ dwt,
    __hip_bfloat16* __restrict__ k1wt,
    int N, int G, int E, int DIN)
{
  const int n0 = N * 32, n1 = G * 2048, n2 = 512 * 32, n3 = 512 * 256;
  const int n4 = G * 224, n5 = 64 * 224, n6 = 192 * 384;
  int idx = blockIdx.x * 256 + threadIdx.x;
  if (idx < n0) { xbf[idx] = __float2bfloat16(x[idx]); return; }
  idx -= n0;
  if (idx < n1) { fpbf[idx] = __float2bfloat16(fp[idx]); return; }
  idx -= n1;
  if (idx < n2) {
    int n = idx / 32, k = idx - n * 32;
    float v = (n < 256) ? c1Wl[k * 256 + n] : c1Wr[k * 256 + (n - 256)];
    wt1[idx] = __float2bfloat16(v); return;
  }
  idx -= n2;
  if (idx < n3) {
    int n = idx / 256, k = idx - n * 256;
    float v = (n < 256) ? c2Wl[k * 256 + n] : c2Wr[k * 256 + (n - 256)];
    wt2[idx] = __float2bfloat16(v); return;
  }
  idx -= n3;
  if (idx < n4) {
    int row = idx / 224, kp = idx - row * 224;
    float v = (kp < DIN) ? desc[(long)row * DIN + kp] : 0.f;
    descbf[idx] = __float2bfloat16(v); return;
  }
  idx -= n4;
  if (idx < n5) {
    int n = idx / 224, kp = idx - n * 224;
    float v = (kp < DIN) ? dW[kp * 64 + n] : 0.f;
    dwt[idx] = __float2bfloat16(v); return;
  }
  idx -= n5;
  if (idx < n6) {
    int n = idx / 384, k = idx - n * 384;
    k1wt[idx] = __float2bfloat16(k1W[k * 192 + n]); return;
  }
  idx -= n6;
  if (idx < E) atomicAdd(&deg[dst[idx]], 1);
}

// ------- LDS-tiled transpose: fW[2048][256] f32 -> fwt[256][2048] bf16 -------
__global__ __launch_bounds__(256) void transpose_fwt_kernel(
    const float* __restrict__ fW, __hip_bfloat16* __restrict__ fwt)
{
  __shared__ float tile[64][65];
  int bk = blockIdx.x * 64, bn = blockIdx.y * 64;
  int tx = threadIdx.x & 63, ty = threadIdx.x >> 6;
#pragma unroll
  for (int j = 0; j < 16; ++j) {
    int kl = ty + j * 4;
    tile[kl][tx] = fW[(long)(bk + kl) * 256 + bn + tx];
  }
  __syncthreads();
#pragma unroll
  for (int j = 0; j < 16; ++j) {
    int nl = ty + j * 4;
    fwt[(long)(bn + nl) * 2048 + bk + tx] = __float2bfloat16(tile[tx][nl]);
  }
}

// ------- bf16 MFMA GEMM: [xl|xr] = A[M][K] @ W[K][512] + bias -> bf16 tables
// Tile 128(M) x 128(N); grid (M/128, 4).
__global__ __launch_bounds__(256) void gemm_mfma_kernel(
    const __hip_bfloat16* __restrict__ A, const __hip_bfloat16* __restrict__ BT,
    const float* __restrict__ bl, const float* __restrict__ br,
    __hip_bfloat16* __restrict__ XL, __hip_bfloat16* __restrict__ XR, int M, int K)
{
  __shared__ short As[128 * 40];
  __shared__ short Bs[128 * 40];
  int bm = blockIdx.x * 128, bn = blockIdx.y * 128;
  int t = threadIdx.x;
  int w = t >> 6, l = t & 63;
  int quad = l >> 4, l16 = l & 15;
  int srow = t >> 1, scol = (t & 1) * 16;

  f32x4 acc[2][8];
#pragma unroll
  for (int i = 0; i < 2; ++i)
#pragma unroll
    for (int j = 0; j < 8; ++j) acc[i][j] = (f32x4){0.f, 0.f, 0.f, 0.f};

  for (int k0 = 0; k0 < K; k0 += 32) {
    *(short8*)&As[srow * 40 + scol] =
        *(const short8*)(const void*)&A[(long)(bm + srow) * K + k0 + scol];
    *(short8*)&As[srow * 40 + scol + 8] =
        *(const short8*)(const void*)&A[(long)(bm + srow) * K + k0 + scol + 8];
    *(short8*)&Bs[srow * 40 + scol] =
        *(const short8*)(const void*)&BT[(long)(bn + srow) * K + k0 + scol];
    *(short8*)&Bs[srow * 40 + scol + 8] =
        *(const short8*)(const void*)&BT[(long)(bn + srow) * K + k0 + scol + 8];
    __syncthreads();
    short8 af[2], bf[8];
#pragma unroll
    for (int mt = 0; mt < 2; ++mt)
      af[mt] = *(short8*)&As[(w * 32 + mt * 16 + l16) * 40 + quad * 8];
#pragma unroll
    for (int nt = 0; nt < 8; ++nt)
      bf[nt] = *(short8*)&Bs[(nt * 16 + l16) * 40 + quad * 8];
#pragma unroll
    for (int mt = 0; mt < 2; ++mt)
#pragma unroll
      for (int nt = 0; nt < 8; ++nt)
        acc[mt][nt] = __builtin_amdgcn_mfma_f32_16x16x32_bf16(af[mt], bf[nt], acc[mt][nt], 0, 0, 0);
    __syncthreads();
  }
#pragma unroll
  for (int mt = 0; mt < 2; ++mt)
#pragma unroll
    for (int nt = 0; nt < 8; ++nt) {
      int col = bn + nt * 16 + l16;
      float b = (col < 256) ? bl[col] : br[col - 256];
#pragma unroll
      for (int r = 0; r < 4; ++r) {
        int row = bm + w * 32 + mt * 16 + quad * 4 + r;
        float v = acc[mt][nt][r] + b;
        if (col < 256)
          XL[(long)row * 256 + col] = __float2bfloat16(v);
        else
          XR[(long)row * 256 + (col - 256)] = __float2bfloat16(v);
      }
    }
}

// ------- bf16 MFMA GEMM + relu + bn epilogue; out bf16 (obf=1) or fp32 -------
__global__ __launch_bounds__(256) void gemm_rb_kernel(
    const __hip_bfloat16* __restrict__ A, const __hip_bfloat16* __restrict__ BT,
    const float* __restrict__ bias, const float* __restrict__ gamma,
    const float* __restrict__ beta, void* __restrict__ out,
    int M, int K, int ldc, int coloff, int obf)
{
  __shared__ short As[64 * 40];
  __shared__ short Bs[64 * 40];
  int bm = blockIdx.x * 64, bn = blockIdx.y * 64;
  int t = threadIdx.x;
  int w = t >> 6, l = t & 63;
  int quad = l >> 4, l16 = l & 15;
  int lrow = t >> 2, col8 = (t & 3) * 8;

  f32x4 acc[4];
#pragma unroll
  for (int nt = 0; nt < 4; ++nt) acc[nt] = (f32x4){0.f, 0.f, 0.f, 0.f};

  for (int k0 = 0; k0 < K; k0 += 32) {
    *(short8*)&As[lrow * 40 + col8] =
        *(const short8*)(const void*)&A[(long)(bm + lrow) * K + k0 + col8];
    *(short8*)&Bs[lrow * 40 + col8] =
        *(const short8*)(const void*)&BT[(long)(bn + lrow) * K + k0 + col8];
    __syncthreads();
    short8 af = *(short8*)&As[(w * 16 + l16) * 40 + quad * 8];
#pragma unroll
    for (int nt = 0; nt < 4; ++nt) {
      short8 bf = *(short8*)&Bs[(nt * 16 + l16) * 40 + quad * 8];
      acc[nt] = __builtin_amdgcn_mfma_f32_16x16x32_bf16(af, bf, acc[nt], 0, 0, 0);
    }
    __syncthreads();
  }
  const float inv = rsqrtf(1.f + 1e-5f);
#pragma unroll
  for (int nt = 0; nt < 4; ++nt) {
    int col = bn + nt * 16 + l16;
    float b = bias[col], gm = gamma[col] * inv, bt = beta[col];
#pragma unroll
    for (int r = 0; r < 4; ++r) {
      int row = bm + w * 16 + quad * 4 + r;
      float v = fmaxf(acc[nt][r] + b, 0.f) * gm + bt;
      if (obf)
        ((__hip_bfloat16*)out)[(long)row * ldc + coloff + col] = __float2bfloat16(v);
      else
        ((float*)out)[(long)row * ldc + coloff + col] = v;
    }
  }
}

// ------- split-K bf16 MFMA (fp branch): grid.z = split; partials -> P fp32 ---
__global__ __launch_bounds__(256) void gemm_skb_kernel(
    const __hip_bfloat16* __restrict__ A, const __hip_bfloat16* __restrict__ BT,
    float* __restrict__ P, int M, int N, int K, int Kc)
{
  __shared__ short As[64 * 40];
  __shared__ short Bs[64 * 40];
  int bm = blockIdx.x * 64, bn = blockIdx.y * 64;
  int s = blockIdx.z;
  int kb = s * Kc, ke = kb + Kc;
  int t = threadIdx.x;
  int w = t >> 6, l = t & 63;
  int quad = l >> 4, l16 = l & 15;
  int lrow = t >> 2, col8 = (t & 3) * 8;

  f32x4 acc[4];
#pragma unroll
  for (int nt = 0; nt < 4; ++nt) acc[nt] = (f32x4){0.f, 0.f, 0.f, 0.f};

  for (int k0 = kb; k0 < ke; k0 += 32) {
    *(short8*)&As[lrow * 40 + col8] =
        *(const short8*)(const void*)&A[(long)(bm + lrow) * K + k0 + col8];
    *(short8*)&Bs[lrow * 40 + col8] =
        *(const short8*)(const void*)&BT[(long)(bn + lrow) * K + k0 + col8];
    __syncthreads();
    short8 af = *(short8*)&As[(w * 16 + l16) * 40 + quad * 8];
#pragma unroll
    for (int nt = 0; nt < 4; ++nt) {
      short8 bf = *(short8*)&Bs[(nt * 16 + l16) * 40 + quad * 8];
      acc[nt] = __builtin_amdgcn_mfma_f32_16x16x32_bf16(af, bf, acc[nt], 0, 0, 0);
    }
    __syncthreads();
  }
#pragma unroll
  for (int nt = 0; nt < 4; ++nt) {
    int col = bn + nt * 16 + l16;
#pragma unroll
    for (int r = 0; r < 4; ++r) {
      int row = bm + w * 16 + quad * 4 + r;
      P[((long)s * M + row) * N + col] = acc[nt][r];
    }
  }
}

// epilogue for fp split-K: sum 4 partials + bias/relu/bn -> zbuf[:,64:320] bf16
__global__ __launch_bounds__(256) void fp_epilogue_kernel(
    const float* __restrict__ P, const float* __restrict__ bias,
    const float* __restrict__ gamma, const float* __restrict__ beta,
    __hip_bfloat16* __restrict__ zbuf, int M, int N, int S)
{
  int idx = blockIdx.x * 256 + threadIdx.x;
  if (idx >= M * N) return;
  int row = idx / N, col = idx - row * N;
  float v = 0.f;
  for (int s = 0; s < S; ++s) v += P[(long)s * M * N + idx];
  const float inv = rsqrtf(1.f + 1e-5f);
  v = fmaxf(v + bias[col], 0.f) * (gamma[col] * inv) + beta[col];
  zbuf[(long)row * 384 + 64 + col] = __float2bfloat16(v);
}

// -------- fused pool + g branch: per-graph colmax (LDS) -> 64-col dense -----
__global__ __launch_bounds__(256) void poolg_kernel(
    const __hip_bfloat16* __restrict__ h, const float* __restrict__ gW,
    const float* __restrict__ gb, const float* __restrict__ g_gn,
    const float* __restrict__ g_bt, __hip_bfloat16* __restrict__ zbuf, int npg)
{
  __shared__ float smax[256];
  __shared__ float sred[256];
  int g = blockIdx.x, t = threadIdx.x;
  const __hip_bfloat16* base = h + (long)g * npg * HC + t;
  float m = -INFINITY;
#pragma unroll 4
  for (int i = 0; i < npg; ++i)
    m = fmaxf(m, bf_to_f32(*(const unsigned short*)&base[(long)i * HC]));
  smax[t] = m;
  __syncthreads();
  int j = t >> 2, part = t & 3;
  float sum = 0.f;
#pragma unroll 4
  for (int k = part * 64; k < part * 64 + 64; ++k)
    sum = fmaf(smax[k], gW[k * 64 + j], sum);
  sred[t] = sum;
  __syncthreads();
  if (t < 64) {
    float v = sred[t * 4] + sred[t * 4 + 1] + sred[t * 4 + 2] + sred[t * 4 + 3];
    const float inv = rsqrtf(1.f + 1e-5f);
    v = fmaxf(v + gb[t], 0.f) * (g_gn[t] * inv) + g_bt[t];
    zbuf[(long)g * 384 + t] = __float2bfloat16(v);
  }
}

// -------- fused k2+k3 head: z1(fp32)[16 rows] -> d_out --------
__global__ __launch_bounds__(256) void head23_kernel(
    const float* __restrict__ z1, const float* __restrict__ k2W,
    const float* __restrict__ k2b, const float* __restrict__ k2_gn,
    const float* __restrict__ k2_bt, const float* __restrict__ k3W,
    const float* __restrict__ k3b, float* __restrict__ out)
{
  __shared__ float s1[16 * 192];
  __shared__ float s2[16 * 96];
  int b = blockIdx.x, t = threadIdx.x;
  for (int i = t; i < 16 * 192; i += 256) s1[i] = z1[(long)b * 16 * 192 + i];
  __syncthreads();
  const float inv = rsqrtf(1.f + 1e-5f);
#pragma unroll
  for (int j = 0; j < 6; ++j) {
    int idx = j * 256 + t;
    int row = idx / 96, col = idx - row * 96;
    float acc = 0.f;
#pragma unroll 4
    for (int k = 0; k < 192; ++k) acc = fmaf(s1[row * 192 + k], k2W[k * 96 + col], acc);
    acc = fmaxf(acc + k2b[col], 0.f);
    s2[idx] = acc * (k2_gn[col] * inv) + k2_bt[col];
  }
  __syncthreads();
  if (t < 192) {
    int row = t / 12, col = t - row * 12;
    float acc = 0.f;
#pragma unroll 4
    for (int k = 0; k < 96; ++k) acc = fmaf(s2[row * 96 + k], k3W[k * 12 + col], acc);
    out[(long)(b * 16 + row) * 12 + col] = acc + k3b[col];
  }
}

// ---------------- CSR build ----------------
__global__ __launch_bounds__(1024) void scan_kernel(
    const int* __restrict__ deg, int* __restrict__ ptr, int* __restrict__ cursor, int N)
{
  __shared__ int sums[1024];
  int t = threadIdx.x;
  int base = t * 32;
  int local[32];
  int s = 0;
#pragma unroll
  for (int i = 0; i < 32; ++i) {
    int v = (base + i < N) ? deg[base + i] : 0;
    local[i] = v; s += v;
  }
  sums[t] = s;
  __syncthreads();
  for (int off = 1; off < 1024; off <<= 1) {
    int v = (t >= off) ? sums[t - off] : 0;
    __syncthreads();
    sums[t] += v;
    __syncthreads();
  }
  int excl = sums[t] - s;
  for (int i = 0; i < 32; ++i) {
    if (base + i < N) { ptr[base + i] = excl; cursor[base + i] = excl; excl += local[i]; }
  }
  if (t == 1023) ptr[N] = sums[1023];
}

// scatter src id AND edge_attr into CSR order
__global__ void fill_kernel(const int* __restrict__ src, const int* __restrict__ dst,
                            const float* __restrict__ ea, int* __restrict__ cursor,
                            int* __restrict__ csr_src, float* __restrict__ csr_ea, int E)
{
  int e = blockIdx.x * blockDim.x + threadIdx.x;
  if (e < E) {
    int pos = atomicAdd(&cursor[dst[e]], 1);
    csr_src[pos] = src[e];
    f32x4 a0 = *(const f32x4*)(const void*)&ea[(long)e * 8];
    f32x4 a1 = *(const f32x4*)(const void*)&ea[(long)e * 8 + 4];
    *(f32x4*)&csr_ea[(long)pos * 8] = a0;
    *(f32x4*)&csr_ea[(long)pos * 8 + 4] = a1;
  }
}

// ---------------- GATv2 aggregation ----------------
// lane = head*16 + quad; lane owns 4 channels of one head; 2 nodes / 128-thr
// block. NO min-waves launch_bounds (R8 lesson: forcing VGPR down -> spills).
// Reduction over 16 lanes via DPP row_ror rotate-reduce (VALU-only) instead of
// ds_swizzle shfl: removes ~110 lgkm-stall cycles/edge (measured VALUBusy 60%
// matched the 160-busy/110-stall model exactly).
__global__ __launch_bounds__(128) void gat_kernel(
    const __hip_bfloat16* __restrict__ xlb, const __hip_bfloat16* __restrict__ xrb,
    const float* __restrict__ csr_ea, const int* __restrict__ csr_src,
    const int* __restrict__ csr_ptr,
    const float* __restrict__ We, const float* __restrict__ att,
    const float* __restrict__ bias, __hip_bfloat16* __restrict__ out, int N)
{
  int lane = threadIdx.x & 63;
  int node = blockIdx.x * 2 + (threadIdx.x >> 6);
  if (node >= N) return;
  int cbase = (lane >> 4) * 64 + (lane & 15) * 4;  // channel offset in [0,256)

  f32x4 attv = *(const f32x4*)(const void*)&att[cbase];
  f32x4 xriv = bf4_to_f32(*(const short4v*)(const void*)&xrb[(long)node * HC + cbase]);
  f32x4 WeR[8];
#pragma unroll
  for (int d = 0; d < 8; ++d)
    WeR[d] = *(const f32x4*)(const void*)&We[d * HC + cbase];

  float rsumA = 0.f, rsumB = 0.f;
  f32x4 accA = (f32x4){0.f, 0.f, 0.f, 0.f};
  f32x4 accB = (f32x4){0.f, 0.f, 0.f, 0.f};
  f32x4 eas0 = (f32x4){0.f, 0.f, 0.f, 0.f};
  f32x4 eas1 = (f32x4){0.f, 0.f, 0.f, 0.f};

  int p0 = csr_ptr[node], p1 = csr_ptr[node + 1];

  auto edge_compute = [&](f32x4 xls, f32x4 ea0, f32x4 ea1,
                          float& rsum, f32x4& acc) {
    f32x4 mv = xriv + xls;
#pragma unroll
    for (int d = 0; d < 4; ++d) mv += WeR[d] * ea0[d];
#pragma unroll
    for (int d = 0; d < 4; ++d) mv += WeR[d + 4] * ea1[d];
    float t = 0.f;
#pragma unroll
    for (int r = 0; r < 4; ++r) {
      float m = mv[r];
      m = (m > 0.f) ? m : 0.2f * m;
      t = fmaf(m, attv[r], t);
    }
    // 16-lane all-reduce via DPP cyclic rotations (ror 1,2,4,8)
    t = dpp_radd<0x121>(t);
    t = dpp_radd<0x122>(t);
    t = dpp_radd<0x124>(t);
    t = dpp_radd<0x128>(t);
    float p = __expf(t);
    rsum += p;
    acc += p * xls;
  };

  // 2-deep prefetch, named slots A/B (runtime-indexed arrays kill codegen)
  short4v xA = (short4v){0, 0, 0, 0}, xB = (short4v){0, 0, 0, 0};
  f32x4 a0A = (f32x4){0.f, 0.f, 0.f, 0.f}, a1A = a0A, a0B = a0A, a1B = a0A;
  if (p0 < p1) {
    int s = csr_src[p0];
    a0A = *(const f32x4*)(const void*)&csr_ea[(long)p0 * 8];
    a1A = *(const f32x4*)(const void*)&csr_ea[(long)p0 * 8 + 4];
    xA = *(const short4v*)(const void*)&xlb[(long)s * HC + cbase];
  }
  if (p0 + 1 < p1) {
    int s = csr_src[p0 + 1];
    a0B = *(const f32x4*)(const void*)&csr_ea[(long)(p0 + 1) * 8];
    a1B = *(const f32x4*)(const void*)&csr_ea[(long)(p0 + 1) * 8 + 4];
    xB = *(const short4v*)(const void*)&xlb[(long)s * HC + cbase];
  }
  int k = p0;
  for (; k + 2 <= p1; k += 2) {
    f32x4 e0a = a0A, e1a = a1A;
    short4v xca = xA;
    if (k + 2 < p1) {
      int s = csr_src[k + 2];
      a0A = *(const f32x4*)(const void*)&csr_ea[(long)(k + 2) * 8];
      a1A = *(const f32x4*)(const void*)&csr_ea[(long)(k + 2) * 8 + 4];
      xA = *(const short4v*)(const void*)&xlb[(long)s * HC + cbase];
    }
    f32x4 e0b = a0B, e1b = a1B;
    short4v xcb = xB;
    if (k + 3 < p1) {
      int s = csr_src[k + 3];
      a0B = *(const f32x4*)(const void*)&csr_ea[(long)(k + 3) * 8];
      a1B = *(const f32x4*)(const void*)&csr_ea[(long)(k + 3) * 8 + 4];
      xB = *(const short4v*)(const void*)&xlb[(long)s * HC + cbase];
    }
    eas0 += e0a + e0b;
    eas1 += e1a + e1b;
    // independent accumulator pairs: the two calls have no data dependency
    edge_compute(bf4_to_f32(xca), e0a, e1a, rsumA, accA);
    edge_compute(bf4_to_f32(xcb), e0b, e1b, rsumB, accB);
  }
  if (k < p1) {           // odd tail lives in slot A
    eas0 += a0A; eas1 += a1A;
    edge_compute(bf4_to_f32(xA), a0A, a1A, rsumA, accA);
  }
  // self loop with mean edge_attr
  int cnt = p1 - p0;
  f32x4 xls_self = bf4_to_f32(*(const short4v*)(const void*)&xlb[(long)node * HC + cbase]);
  float invd = 1.f / (float)(cnt > 1 ? cnt : 1);
  edge_compute(xls_self, eas0 * invd, eas1 * invd, rsumB, accB);

  float invs = 1.f / (rsumA + rsumB);
  f32x4 biasv = *(const f32x4*)(const void*)&bias[cbase];
  short4v pk;
#pragma unroll
  for (int r = 0; r < 4; ++r) {
    float v = fmaxf((accA[r] + accB[r]) * invs + biasv[r], 0.f);
    __hip_bfloat16 hv = __float2bfloat16(v);
    pk[r] = *(short*)&hv;
  }
  *(short4v*)&out[(long)node * HC + cbase] = pk;
}

extern "C" void kernel_launch(void* const* d_in, const int* in_sizes, int n_in,
                              void* d_out, int out_size, void* d_ws, size_t ws_size,
                              hipStream_t stream)
{
  const float* x          = (const float*)d_in[0];
  const int*   edge_index = (const int*)d_in[1];
  const float* edge_attr  = (const float*)d_in[2];
  const float* fp         = (const float*)d_in[4];
  const float* desc       = (const float*)d_in[5];
  const float *c1_Wl = (const float*)d_in[6],  *c1_bl = (const float*)d_in[7],
              *c1_Wr = (const float*)d_in[8],  *c1_br = (const float*)d_in[9],
              *c1_We = (const float*)d_in[10], *c1_att = (const float*)d_in[11],
              *c1_bias = (const float*)d_in[12];
  const float *c2_Wl = (const float*)d_in[13], *c2_bl = (const float*)d_in[14],
              *c2_Wr = (const float*)d_in[15], *c2_br = (const float*)d_in[16],
              *c2_We = (const float*)d_in[17], *c2_att = (const float*)d_in[18],
              *c2_bias = (const float*)d_in[19];
  const float *gW = (const float*)d_in[20], *gb = (const float*)d_in[21],
              *g_gn = (const float*)d_in[22], *g_bt = (const float*)d_in[23];
  const float *fW = (const float*)d_in[24], *fb = (const float*)d_in[25],
              *f_gn = (const float*)d_in[26], *f_bt = (const float*)d_in[27];
  const float *dW = (const float*)d_in[28], *db = (const float*)d_in[29],
              *d_gn = (const float*)d_in[30], *d_bt = (const float*)d_in[31];
  const float *k1W = (const float*)d_in[32], *k1b = (const float*)d_in[33],
              *k1_gn = (const float*)d_in[34], *k1_bt = (const float*)d_in[35];
  const float *k2W = (const float*)d_in[36], *k2b = (const float*)d_in[37],
              *k2_gn = (const float*)d_in[38], *k2_bt = (const float*)d_in[39];
  const float *k3W = (const float*)d_in[40], *k3b = (const float*)d_in[41];

  const int N = in_sizes[0] / 32;       // 32768
  const int E = in_sizes[1] / 2;        // 262144
  const int G = in_sizes[4] / 2048;     // 1024
  const int FIN = 32, FPIN = 2048;
  const int DIN = in_sizes[5] / G;      // 200

  char* ws = (char*)d_ws;
  size_t off = 0;
  auto alloc = [&](size_t bytes) {
    void* p = ws + off;
    off = (off + bytes + 255) & ~(size_t)255;
    return p;
  };
  __hip_bfloat16* xlb    = (__hip_bfloat16*)alloc((size_t)N * HC * 2);  // 16 MB
  __hip_bfloat16* xrb    = (__hip_bfloat16*)alloc((size_t)N * HC * 2);  // 16 MB
  __hip_bfloat16* hb1    = (__hip_bfloat16*)alloc((size_t)N * HC * 2);  // 16 MB
  __hip_bfloat16* hb2    = (__hip_bfloat16*)alloc((size_t)N * HC * 2);  // 16 MB
  __hip_bfloat16* xbf    = (__hip_bfloat16*)alloc((size_t)N * FIN * 2);
  __hip_bfloat16* fpbf   = (__hip_bfloat16*)alloc((size_t)G * FPIN * 2); // 4 MB
  __hip_bfloat16* wt1    = (__hip_bfloat16*)alloc((size_t)512 * FIN * 2);
  __hip_bfloat16* wt2    = (__hip_bfloat16*)alloc((size_t)512 * HC * 2);
  __hip_bfloat16* fwt    = (__hip_bfloat16*)alloc((size_t)256 * FPIN * 2); // 1 MB
  __hip_bfloat16* descbf = (__hip_bfloat16*)alloc((size_t)G * 224 * 2);
  __hip_bfloat16* dwt    = (__hip_bfloat16*)alloc((size_t)64 * 224 * 2);
  __hip_bfloat16* k1wt   = (__hip_bfloat16*)alloc((size_t)192 * 384 * 2);
  __hip_bfloat16* zbuf   = (__hip_bfloat16*)alloc((size_t)G * 384 * 2);
  float* z1      = (float*)alloc((size_t)G * 192 * 4);
  float* P_fp    = (float*)alloc((size_t)4 * G * 256 * 4);             // 4 MB
  int*   deg     = (int*)alloc((size_t)N * 4);
  int*   csr_ptr = (int*)alloc((size_t)(N + 1) * 4);
  int*   cursor  = (int*)alloc((size_t)N * 4);
  int*   csr_src = (int*)alloc((size_t)E * 4);
  float* csr_ea  = (float*)alloc((size_t)E * 8 * 4);                  // 8 MB
  (void)ws_size;

  const int* srcp = edge_index;
  const int* dstp = edge_index + E;

  hipMemsetAsync(deg, 0, (size_t)N * 4, stream);

  // prep: conversions + weight transposes + padded desc + k1W^T + degree count
  {
    long total = (long)N * FIN + (long)G * FPIN + 512 * 32 + 512 * 256 +
                 (long)G * 224 + 64 * 224 + 192 * 384 + E;
    prep_kernel<<<(int)((total + 255) / 256), 256, 0, stream>>>(
        x, fp, c1_Wl, c1_Wr, c2_Wl, c2_Wr, desc, dW, k1W, dstp, deg,
        xbf, fpbf, wt1, wt2, descbf, dwt, k1wt, N, G, E, DIN);
  }
  transpose_fwt_kernel<<<dim3(2048 / 64, 256 / 64), 256, 0, stream>>>(fW, fwt);
  scan_kernel<<<1, 1024, 0, stream>>>(deg, csr_ptr, cursor, N);
  fill_kernel<<<(E + 255) / 256, 256, 0, stream>>>(srcp, dstp, edge_attr, cursor,
                                                   csr_src, csr_ea, E);

  // fp branch: split-K MFMA (256 blocks) + epilogue -> zbuf[:,64:320]
  gemm_skb_kernel<<<dim3(G / 64, 4, 4), 256, 0, stream>>>(fpbf, fwt, P_fp,
                                                          G, 256, FPIN, FPIN / 4);
  fp_epilogue_kernel<<<(G * 256 + 255) / 256, 256, 0, stream>>>(P_fp, fb, f_gn, f_bt,
                                                                zbuf, G, 256, 4);
  // desc branch (bf16 MFMA, K padded to 224) -> zbuf[:,320:384]
  gemm_rb_kernel<<<dim3(G / 64, 1), 256, 0, stream>>>(descbf, dwt, db, d_gn, d_bt,
                                                      zbuf, G, 224, 384, 320, 1);

  // layer 1
  gemm_mfma_kernel<<<dim3(N / 128, 4), 256, 0, stream>>>(xbf, wt1, c1_bl, c1_br, xlb, xrb, N, FIN);
  gat_kernel<<<N / 2, 128, 0, stream>>>(xlb, xrb, csr_ea, csr_src, csr_ptr,
                                        c1_We, c1_att, c1_bias, hb1, N);
  // layer 2
  gemm_mfma_kernel<<<dim3(N / 128, 4), 256, 0, stream>>>(hb1, wt2, c2_bl, c2_br, xlb, xrb, N, HC);
  gat_kernel<<<N / 2, 128, 0, stream>>>(xlb, xrb, csr_ea, csr_src, csr_ptr,
                                        c2_We, c2_att, c2_bias, hb2, N);

  // fused pool + g branch -> zbuf[:,0:64]
  poolg_kernel<<<G, 256, 0, stream>>>(hb2, gW, gb, g_gn, g_bt, zbuf, N / G);

  // k1 (bf16 MFMA) -> z1 fp32
  gemm_rb_kernel<<<dim3(G / 64, 3), 256, 0, stream>>>(zbuf, k1wt, k1b, k1_gn, k1_bt,
                                                      z1, G, 384, 192, 0, 0);
  // k2+k3 head
  head23_kernel<<<G / 16, 256, 0, stream>>>(z1, k2W, k2b, k2_gn, k2_bt, k3W, k3b,
                                            (float*)d_out);
}

// Round 14
// 449.260 us; speedup vs baseline: 1.2845x; 1.1011x over previous
//
#include <hip/hip_runtime.h>
#include <hip/hip_bf16.h>
#include <math.h>

#define NHEAD 4
#define HC 256

typedef short short8 __attribute__((ext_vector_type(8)));
typedef short short4v __attribute__((ext_vector_type(4)));
typedef float f32x4 __attribute__((ext_vector_type(4)));

__device__ inline f32x4 bf4_to_f32(short4v v)
{
  f32x4 r;
#pragma unroll
  for (int i = 0; i < 4; ++i)
    r[i] = __uint_as_float(((unsigned)(unsigned short)v[i]) << 16);
  return r;
}

__device__ inline float bf_to_f32(unsigned short u)
{
  return __uint_as_float(((unsigned)u) << 16);
}

// DPP rotate-add within a row of 16 lanes (VALU-only).
template <int CTRL>
__device__ inline float dpp_radd(float x)
{
  int yi = __builtin_amdgcn_update_dpp(0, __float_as_int(x), CTRL, 0xf, 0xf, true);
  return x + __int_as_float(yi);
}

// ------- one fused prep kernel: fp32->bf16 conversions, weight transposes,
// desc/dW zero-padded to K=224, k1W^T, and the degree count -------
__global__ void prep_kernel(
    const float* __restrict__ x, const float* __restrict__ fp,
    const float* __restrict__ c1Wl, const float* __restrict__ c1Wr,
    const float* __restrict__ c2Wl, const float* __restrict__ c2Wr,
    const float* __restrict__ desc, const float* __restrict__ dW,
    const float* __restrict__ k1W,
    const int* __restrict__ dst, int* __restrict__ deg,
    __hip_bfloat16* __restrict__ xbf, __hip_bfloat16* __restrict__ fpbf,
    __hip_bfloat16* __restrict__ wt1, __hip_bfloat16* __restrict__ wt2,
    __hip_bfloat16* __restrict__ descbf, __hip_bfloat16* __restrict__ dwt,
    __hip_bfloat16* __restrict__ k1wt,
    int N, int G, int E, int DIN)
{
  const int n0 = N * 32, n1 = G * 2048, n2 = 512 * 32, n3 = 512 * 256;
  const int n4 = G * 224, n5 = 64 * 224, n6 = 192 * 384;
  int idx = blockIdx.x * 256 + threadIdx.x;
  if (idx < n0) { xbf[idx] = __float2bfloat16(x[idx]); return; }
  idx -= n0;
  if (idx < n1) { fpbf[idx] = __float2bfloat16(fp[idx]); return; }
  idx -= n1;
  if (idx < n2) {
    int n = idx / 32, k = idx - n * 32;
    float v = (n < 256) ? c1Wl[k * 256 + n] : c1Wr[k * 256 + (n - 256)];
    wt1[idx] = __float2bfloat16(v); return;
  }
  idx -= n2;
  if (idx < n3) {
    int n = idx / 256, k = idx - n * 256;
    float v = (n < 256) ? c2Wl[k * 256 + n] : c2Wr[k * 256 + (n - 256)];
    wt2[idx] = __float2bfloat16(v); return;
  }
  idx -= n3;
  if (idx < n4) {
    int row = idx / 224, kp = idx - row * 224;
    float v = (kp < DIN) ? desc[(long)row * DIN + kp] : 0.f;
    descbf[idx] = __float2bfloat16(v); return;
  }
  idx -= n4;
  if (idx < n5) {
    int n = idx / 224, kp = idx - n * 224;
    float v = (kp < DIN) ? dW[kp * 64 + n] : 0.f;
    dwt[idx] = __float2bfloat16(v); return;
  }
  idx -= n5;
  if (idx < n6) {
    int n = idx / 384, k = idx - n * 384;
    k1wt[idx] = __float2bfloat16(k1W[k * 192 + n]); return;
  }
  idx -= n6;
  if (idx < E) atomicAdd(&deg[dst[idx]], 1);
}

// ------- LDS-tiled transpose: fW[2048][256] f32 -> fwt[256][2048] bf16 -------
__global__ __launch_bounds__(256) void transpose_fwt_kernel(
    const float* __restrict__ fW, __hip_bfloat16* __restrict__ fwt)
{
  __shared__ float tile[64][65];
  int bk = blockIdx.x * 64, bn = blockIdx.y * 64;
  int tx = threadIdx.x & 63, ty = threadIdx.x >> 6;
#pragma unroll
  for (int j = 0; j < 16; ++j) {
    int kl = ty + j * 4;
    tile[kl][tx] = fW[(long)(bk + kl) * 256 + bn + tx];
  }
  __syncthreads();
#pragma unroll
  for (int j = 0; j < 16; ++j) {
    int nl = ty + j * 4;
    fwt[(long)(bn + nl) * 2048 + bk + tx] = __float2bfloat16(tile[tx][nl]);
  }
}

// ------- bf16 MFMA GEMM: [xl|xr] = A[M][K] @ W[K][512] + bias -> bf16 tables
__global__ __launch_bounds__(256) void gemm_mfma_kernel(
    const __hip_bfloat16* __restrict__ A, const __hip_bfloat16* __restrict__ BT,
    const float* __restrict__ bl, const float* __restrict__ br,
    __hip_bfloat16* __restrict__ XL, __hip_bfloat16* __restrict__ XR, int M, int K)
{
  __shared__ short As[128 * 40];
  __shared__ short Bs[128 * 40];
  int bm = blockIdx.x * 128, bn = blockIdx.y * 128;
  int t = threadIdx.x;
  int w = t >> 6, l = t & 63;
  int quad = l >> 4, l16 = l & 15;
  int srow = t >> 1, scol = (t & 1) * 16;

  f32x4 acc[2][8];
#pragma unroll
  for (int i = 0; i < 2; ++i)
#pragma unroll
    for (int j = 0; j < 8; ++j) acc[i][j] = (f32x4){0.f, 0.f, 0.f, 0.f};

  for (int k0 = 0; k0 < K; k0 += 32) {
    *(short8*)&As[srow * 40 + scol] =
        *(const short8*)(const void*)&A[(long)(bm + srow) * K + k0 + scol];
    *(short8*)&As[srow * 40 + scol + 8] =
        *(const short8*)(const void*)&A[(long)(bm + srow) * K + k0 + scol + 8];
    *(short8*)&Bs[srow * 40 + scol] =
        *(const short8*)(const void*)&BT[(long)(bn + srow) * K + k0 + scol];
    *(short8*)&Bs[srow * 40 + scol + 8] =
        *(const short8*)(const void*)&BT[(long)(bn + srow) * K + k0 + scol + 8];
    __syncthreads();
    short8 af[2], bf[8];
#pragma unroll
    for (int mt = 0; mt < 2; ++mt)
      af[mt] = *(short8*)&As[(w * 32 + mt * 16 + l16) * 40 + quad * 8];
#pragma unroll
    for (int nt = 0; nt < 8; ++nt)
      bf[nt] = *(short8*)&Bs[(nt * 16 + l16) * 40 + quad * 8];
#pragma unroll
    for (int mt = 0; mt < 2; ++mt)
#pragma unroll
      for (int nt = 0; nt < 8; ++nt)
        acc[mt][nt] = __builtin_amdgcn_mfma_f32_16x16x32_bf16(af[mt], bf[nt], acc[mt][nt], 0, 0, 0);
    __syncthreads();
  }
#pragma unroll
  for (int mt = 0; mt < 2; ++mt)
#pragma unroll
    for (int nt = 0; nt < 8; ++nt) {
      int col = bn + nt * 16 + l16;
      float b = (col < 256) ? bl[col] : br[col - 256];
#pragma unroll
      for (int r = 0; r < 4; ++r) {
        int row = bm + w * 32 + mt * 16 + quad * 4 + r;
        float v = acc[mt][nt][r] + b;
        if (col < 256)
          XL[(long)row * 256 + col] = __float2bfloat16(v);
        else
          XR[(long)row * 256 + (col - 256)] = __float2bfloat16(v);
      }
    }
}

// ------- bf16 MFMA GEMM + relu + bn epilogue; out bf16 (obf=1) or fp32 -------
__global__ __launch_bounds__(256) void gemm_rb_kernel(
    const __hip_bfloat16* __restrict__ A, const __hip_bfloat16* __restrict__ BT,
    const float* __restrict__ bias, const float* __restrict__ gamma,
    const float* __restrict__ beta, void* __restrict__ out,
    int M, int K, int ldc, int coloff, int obf)
{
  __shared__ short As[64 * 40];
  __shared__ short Bs[64 * 40];
  int bm = blockIdx.x * 64, bn = blockIdx.y * 64;
  int t = threadIdx.x;
  int w = t >> 6, l = t & 63;
  int quad = l >> 4, l16 = l & 15;
  int lrow = t >> 2, col8 = (t & 3) * 8;

  f32x4 acc[4];
#pragma unroll
  for (int nt = 0; nt < 4; ++nt) acc[nt] = (f32x4){0.f, 0.f, 0.f, 0.f};

  for (int k0 = 0; k0 < K; k0 += 32) {
    *(short8*)&As[lrow * 40 + col8] =
        *(const short8*)(const void*)&A[(long)(bm + lrow) * K + k0 + col8];
    *(short8*)&Bs[lrow * 40 + col8] =
        *(const short8*)(const void*)&BT[(long)(bn + lrow) * K + k0 + col8];
    __syncthreads();
    short8 af = *(short8*)&As[(w * 16 + l16) * 40 + quad * 8];
#pragma unroll
    for (int nt = 0; nt < 4; ++nt) {
      short8 bf = *(short8*)&Bs[(nt * 16 + l16) * 40 + quad * 8];
      acc[nt] = __builtin_amdgcn_mfma_f32_16x16x32_bf16(af, bf, acc[nt], 0, 0, 0);
    }
    __syncthreads();
  }
  const float inv = rsqrtf(1.f + 1e-5f);
#pragma unroll
  for (int nt = 0; nt < 4; ++nt) {
    int col = bn + nt * 16 + l16;
    float b = bias[col], gm = gamma[col] * inv, bt = beta[col];
#pragma unroll
    for (int r = 0; r < 4; ++r) {
      int row = bm + w * 16 + quad * 4 + r;
      float v = fmaxf(acc[nt][r] + b, 0.f) * gm + bt;
      if (obf)
        ((__hip_bfloat16*)out)[(long)row * ldc + coloff + col] = __float2bfloat16(v);
      else
        ((float*)out)[(long)row * ldc + coloff + col] = v;
    }
  }
}

// ------- split-K bf16 MFMA (fp branch): grid.z = split; partials -> P fp32 ---
__global__ __launch_bounds__(256) void gemm_skb_kernel(
    const __hip_bfloat16* __restrict__ A, const __hip_bfloat16* __restrict__ BT,
    float* __restrict__ P, int M, int N, int K, int Kc)
{
  __shared__ short As[64 * 40];
  __shared__ short Bs[64 * 40];
  int bm = blockIdx.x * 64, bn = blockIdx.y * 64;
  int s = blockIdx.z;
  int kb = s * Kc, ke = kb + Kc;
  int t = threadIdx.x;
  int w = t >> 6, l = t & 63;
  int quad = l >> 4, l16 = l & 15;
  int lrow = t >> 2, col8 = (t & 3) * 8;

  f32x4 acc[4];
#pragma unroll
  for (int nt = 0; nt < 4; ++nt) acc[nt] = (f32x4){0.f, 0.f, 0.f, 0.f};

  for (int k0 = kb; k0 < ke; k0 += 32) {
    *(short8*)&As[lrow * 40 + col8] =
        *(const short8*)(const void*)&A[(long)(bm + lrow) * K + k0 + col8];
    *(short8*)&Bs[lrow * 40 + col8] =
        *(const short8*)(const void*)&BT[(long)(bn + lrow) * K + k0 + col8];
    __syncthreads();
    short8 af = *(short8*)&As[(w * 16 + l16) * 40 + quad * 8];
#pragma unroll
    for (int nt = 0; nt < 4; ++nt) {
      short8 bf = *(short8*)&Bs[(nt * 16 + l16) * 40 + quad * 8];
      acc[nt] = __builtin_amdgcn_mfma_f32_16x16x32_bf16(af, bf, acc[nt], 0, 0, 0);
    }
    __syncthreads();
  }
#pragma unroll
  for (int nt = 0; nt < 4; ++nt) {
    int col = bn + nt * 16 + l16;
#pragma unroll
    for (int r = 0; r < 4; ++r) {
      int row = bm + w * 16 + quad * 4 + r;
      P[((long)s * M + row) * N + col] = acc[nt][r];
    }
  }
}

// epilogue for fp split-K: sum 4 partials + bias/relu/bn -> zbuf[:,64:320] bf16
__global__ __launch_bounds__(256) void fp_epilogue_kernel(
    const float* __restrict__ P, const float* __restrict__ bias,
    const float* __restrict__ gamma, const float* __restrict__ beta,
    __hip_bfloat16* __restrict__ zbuf, int M, int N, int S)
{
  int idx = blockIdx.x * 256 + threadIdx.x;
  if (idx >= M * N) return;
  int row = idx / N, col = idx - row * N;
  float v = 0.f;
  for (int s = 0; s < S; ++s) v += P[(long)s * M * N + idx];
  const float inv = rsqrtf(1.f + 1e-5f);
  v = fmaxf(v + bias[col], 0.f) * (gamma[col] * inv) + beta[col];
  zbuf[(long)row * 384 + 64 + col] = __float2bfloat16(v);
}

// -------- fused pool + g branch: per-graph colmax (LDS) -> 64-col dense -----
__global__ __launch_bounds__(256) void poolg_kernel(
    const __hip_bfloat16* __restrict__ h, const float* __restrict__ gW,
    const float* __restrict__ gb, const float* __restrict__ g_gn,
    const float* __restrict__ g_bt, __hip_bfloat16* __restrict__ zbuf, int npg)
{
  __shared__ float smax[256];
  __shared__ float sred[256];
  int g = blockIdx.x, t = threadIdx.x;
  const __hip_bfloat16* base = h + (long)g * npg * HC + t;
  float m = -INFINITY;
#pragma unroll 4
  for (int i = 0; i < npg; ++i)
    m = fmaxf(m, bf_to_f32(*(const unsigned short*)&base[(long)i * HC]));
  smax[t] = m;
  __syncthreads();
  int j = t >> 2, part = t & 3;
  float sum = 0.f;
#pragma unroll 4
  for (int k = part * 64; k < part * 64 + 64; ++k)
    sum = fmaf(smax[k], gW[k * 64 + j], sum);
  sred[t] = sum;
  __syncthreads();
  if (t < 64) {
    float v = sred[t * 4] + sred[t * 4 + 1] + sred[t * 4 + 2] + sred[t * 4 + 3];
    const float inv = rsqrtf(1.f + 1e-5f);
    v = fmaxf(v + gb[t], 0.f) * (g_gn[t] * inv) + g_bt[t];
    zbuf[(long)g * 384 + t] = __float2bfloat16(v);
  }
}

// -------- fused k2+k3 head: z1(fp32)[16 rows] -> d_out --------
__global__ __launch_bounds__(256) void head23_kernel(
    const float* __restrict__ z1, const float* __restrict__ k2W,
    const float* __restrict__ k2b, const float* __restrict__ k2_gn,
    const float* __restrict__ k2_bt, const float* __restrict__ k3W,
    const float* __restrict__ k3b, float* __restrict__ out)
{
  __shared__ float s1[16 * 192];
  __shared__ float s2[16 * 96];
  int b = blockIdx.x, t = threadIdx.x;
  for (int i = t; i < 16 * 192; i += 256) s1[i] = z1[(long)b * 16 * 192 + i];
  __syncthreads();
  const float inv = rsqrtf(1.f + 1e-5f);
#pragma unroll
  for (int j = 0; j < 6; ++j) {
    int idx = j * 256 + t;
    int row = idx / 96, col = idx - row * 96;
    float acc = 0.f;
#pragma unroll 4
    for (int k = 0; k < 192; ++k) acc = fmaf(s1[row * 192 + k], k2W[k * 96 + col], acc);
    acc = fmaxf(acc + k2b[col], 0.f);
    s2[idx] = acc * (k2_gn[col] * inv) + k2_bt[col];
  }
  __syncthreads();
  if (t < 192) {
    int row = t / 12, col = t - row * 12;
    float acc = 0.f;
#pragma unroll 4
    for (int k = 0; k < 96; ++k) acc = fmaf(s2[row * 96 + k], k3W[k * 12 + col], acc);
    out[(long)(b * 16 + row) * 12 + col] = acc + k3b[col];
  }
}

// ---------------- CSR build: 2-pass coalesced scan ----------------
// pass 1: block-local exclusive scan of deg (1024/block), block totals -> bsum
__global__ __launch_bounds__(1024) void scan1_kernel(
    const int* __restrict__ deg, int* __restrict__ ptr,
    int* __restrict__ bsum, int N)
{
  __shared__ int s[1024];
  int b = blockIdx.x, t = threadIdx.x;
  int i = b * 1024 + t;
  int v = (i < N) ? deg[i] : 0;
  s[t] = v;
  __syncthreads();
  for (int off = 1; off < 1024; off <<= 1) {
    int x = (t >= off) ? s[t - off] : 0;
    __syncthreads();
    s[t] += x;
    __syncthreads();
  }
  if (i < N) ptr[i] = s[t] - v;   // local exclusive prefix
  if (t == 1023) bsum[b] = s[1023];
}

// pass 2: add block offsets; write cursor and ptr[N]
__global__ __launch_bounds__(256) void scan2_kernel(
    const int* __restrict__ bsum, int* __restrict__ ptr,
    int* __restrict__ cursor, int N, int nb)
{
  int i = blockIdx.x * 256 + threadIdx.x;
  if (i > N) return;
  if (i == N) {
    int tot = 0;
    for (int j = 0; j < nb; ++j) tot += bsum[j];
    ptr[N] = tot;
    return;
  }
  int b = i >> 10;
  int offv = 0;
  for (int j = 0; j < b; ++j) offv += bsum[j];
  int v = ptr[i] + offv;
  ptr[i] = v;
  cursor[i] = v;
}

// scatter src id AND edge_attr into CSR order
__global__ void fill_kernel(const int* __restrict__ src, const int* __restrict__ dst,
                            const float* __restrict__ ea, int* __restrict__ cursor,
                            int* __restrict__ csr_src, float* __restrict__ csr_ea, int E)
{
  int e = blockIdx.x * blockDim.x + threadIdx.x;
  if (e < E) {
    int pos = atomicAdd(&cursor[dst[e]], 1);
    csr_src[pos] = src[e];
    f32x4 a0 = *(const f32x4*)(const void*)&ea[(long)e * 8];
    f32x4 a1 = *(const f32x4*)(const void*)&ea[(long)e * 8 + 4];
    *(f32x4*)&csr_ea[(long)pos * 8] = a0;
    *(f32x4*)&csr_ea[(long)pos * 8 + 4] = a1;
  }
}

// per-node mean of edge_attr (for the self loop); idx = node*8 + d
__global__ __launch_bounds__(256) void eamean_kernel(
    const float* __restrict__ csr_ea, const int* __restrict__ csr_ptr,
    float* __restrict__ ea_mean, int N)
{
  int idx = blockIdx.x * 256 + threadIdx.x;
  if (idx >= N * 8) return;
  int node = idx >> 3, d = idx & 7;
  int p0 = csr_ptr[node], p1 = csr_ptr[node + 1];
  float s = 0.f;
  for (int k = p0; k < p1; ++k) s += csr_ea[(long)k * 8 + d];
  int cnt = p1 - p0;
  ea_mean[idx] = s / (float)(cnt > 1 ? cnt : 1);
}

// ---------------- GATv2 aggregation ----------------
// lane = head*16 + quad; lane owns 4 channels of one head; 2 nodes / 128-thr
// block. NO min-waves launch_bounds (R8 lesson). DPP rotate-reduce for the
// 16-lane logit sum. 3-deep NAMED prefetch (A/B/C) to cover the ~200-400cyc
// L2 gather latency (R13: VALUBusy stuck at 58% with depth 2 -> gather-bound).
// Self-loop edge_attr mean precomputed in eamean_kernel (frees eas registers
// and 8 VALU/edge).
__global__ __launch_bounds__(128) void gat_kernel(
    const __hip_bfloat16* __restrict__ xlb, const __hip_bfloat16* __restrict__ xrb,
    const float* __restrict__ csr_ea, const int* __restrict__ csr_src,
    const int* __restrict__ csr_ptr, const float* __restrict__ ea_mean,
    const float* __restrict__ We, const float* __restrict__ att,
    const float* __restrict__ bias, __hip_bfloat16* __restrict__ out, int N)
{
  int lane = threadIdx.x & 63;
  int node = blockIdx.x * 2 + (threadIdx.x >> 6);
  if (node >= N) return;
  int cbase = (lane >> 4) * 64 + (lane & 15) * 4;  // channel offset in [0,256)

  f32x4 attv = *(const f32x4*)(const void*)&att[cbase];
  f32x4 xriv = bf4_to_f32(*(const short4v*)(const void*)&xrb[(long)node * HC + cbase]);
  f32x4 WeR[8];
#pragma unroll
  for (int d = 0; d < 8; ++d)
    WeR[d] = *(const f32x4*)(const void*)&We[d * HC + cbase];

  float rsumA = 0.f, rsumB = 0.f;
  f32x4 accA = (f32x4){0.f, 0.f, 0.f, 0.f};
  f32x4 accB = (f32x4){0.f, 0.f, 0.f, 0.f};

  int p0 = csr_ptr[node], p1 = csr_ptr[node + 1];

  auto edge_compute = [&](f32x4 xls, f32x4 ea0, f32x4 ea1,
                          float& rsum, f32x4& acc) {
    f32x4 mv = xriv + xls;
#pragma unroll
    for (int d = 0; d < 4; ++d) mv += WeR[d] * ea0[d];
#pragma unroll
    for (int d = 0; d < 4; ++d) mv += WeR[d + 4] * ea1[d];
    float t = 0.f;
#pragma unroll
    for (int r = 0; r < 4; ++r) {
      float m = mv[r];
      m = (m > 0.f) ? m : 0.2f * m;
      t = fmaf(m, attv[r], t);
    }
    t = dpp_radd<0x121>(t);
    t = dpp_radd<0x122>(t);
    t = dpp_radd<0x124>(t);
    t = dpp_radd<0x128>(t);
    float p = __expf(t);
    rsum += p;
    acc += p * xls;
  };

  // 3-deep prefetch, named slots A/B/C
  short4v xA = (short4v){0, 0, 0, 0}, xB = xA, xC = xA;
  f32x4 a0A = (f32x4){0.f, 0.f, 0.f, 0.f}, a1A = a0A;
  f32x4 a0B = a0A, a1B = a0A, a0C = a0A, a1C = a0A;
  if (p0 < p1) {
    int s = csr_src[p0];
    a0A = *(const f32x4*)(const void*)&csr_ea[(long)p0 * 8];
    a1A = *(const f32x4*)(const void*)&csr_ea[(long)p0 * 8 + 4];
    xA = *(const short4v*)(const void*)&xlb[(long)s * HC + cbase];
  }
  if (p0 + 1 < p1) {
    int s = csr_src[p0 + 1];
    a0B = *(const f32x4*)(const void*)&csr_ea[(long)(p0 + 1) * 8];
    a1B = *(const f32x4*)(const void*)&csr_ea[(long)(p0 + 1) * 8 + 4];
    xB = *(const short4v*)(const void*)&xlb[(long)s * HC + cbase];
  }
  if (p0 + 2 < p1) {
    int s = csr_src[p0 + 2];
    a0C = *(const f32x4*)(const void*)&csr_ea[(long)(p0 + 2) * 8];
    a1C = *(const f32x4*)(const void*)&csr_ea[(long)(p0 + 2) * 8 + 4];
    xC = *(const short4v*)(const void*)&xlb[(long)s * HC + cbase];
  }
  int k = p0;
  for (; k + 3 <= p1; k += 3) {
    f32x4 e0 = a0A, e1 = a1A;
    short4v xc = xA;
    if (k + 3 < p1) {
      int s = csr_src[k + 3];
      a0A = *(const f32x4*)(const void*)&csr_ea[(long)(k + 3) * 8];
      a1A = *(const f32x4*)(const void*)&csr_ea[(long)(k + 3) * 8 + 4];
      xA = *(const short4v*)(const void*)&xlb[(long)s * HC + cbase];
    }
    edge_compute(bf4_to_f32(xc), e0, e1, rsumA, accA);

    e0 = a0B; e1 = a1B; xc = xB;
    if (k + 4 < p1) {
      int s = csr_src[k + 4];
      a0B = *(const f32x4*)(const void*)&csr_ea[(long)(k + 4) * 8];
      a1B = *(const f32x4*)(const void*)&csr_ea[(long)(k + 4) * 8 + 4];
      xB = *(const short4v*)(const void*)&xlb[(long)s * HC + cbase];
    }
    edge_compute(bf4_to_f32(xc), e0, e1, rsumB, accB);

    e0 = a0C; e1 = a1C; xc = xC;
    if (k + 5 < p1) {
      int s = csr_src[k + 5];
      a0C = *(const f32x4*)(const void*)&csr_ea[(long)(k + 5) * 8];
      a1C = *(const f32x4*)(const void*)&csr_ea[(long)(k + 5) * 8 + 4];
      xC = *(const short4v*)(const void*)&xlb[(long)s * HC + cbase];
    }
    edge_compute(bf4_to_f32(xc), e0, e1, rsumA, accA);
  }
  // tail (0..2 edges, in slots A then B)
  if (k < p1)     edge_compute(bf4_to_f32(xA), a0A, a1A, rsumA, accA);
  if (k + 1 < p1) edge_compute(bf4_to_f32(xB), a0B, a1B, rsumB, accB);

  // self loop with precomputed mean edge_attr
  f32x4 em0 = *(const f32x4*)(const void*)&ea_mean[(long)node * 8];
  f32x4 em1 = *(const f32x4*)(const void*)&ea_mean[(long)node * 8 + 4];
  f32x4 xls_self = bf4_to_f32(*(const short4v*)(const void*)&xlb[(long)node * HC + cbase]);
  edge_compute(xls_self, em0, em1, rsumB, accB);

  float invs = 1.f / (rsumA + rsumB);
  f32x4 biasv = *(const f32x4*)(const void*)&bias[cbase];
  short4v pk;
#pragma unroll
  for (int r = 0; r < 4; ++r) {
    float v = fmaxf((accA[r] + accB[r]) * invs + biasv[r], 0.f);
    __hip_bfloat16 hv = __float2bfloat16(v);
    pk[r] = *(short*)&hv;
  }
  *(short4v*)&out[(long)node * HC + cbase] = pk;
}

extern "C" void kernel_launch(void* const* d_in, const int* in_sizes, int n_in,
                              void* d_out, int out_size, void* d_ws, size_t ws_size,
                              hipStream_t stream)
{
  const float* x          = (const float*)d_in[0];
  const int*   edge_index = (const int*)d_in[1];
  const float* edge_attr  = (const float*)d_in[2];
  const float* fp         = (const float*)d_in[4];
  const float* desc       = (const float*)d_in[5];
  const float *c1_Wl = (const float*)d_in[6],  *c1_bl = (const float*)d_in[7],
              *c1_Wr = (const float*)d_in[8],  *c1_br = (const float*)d_in[9],
              *c1_We = (const float*)d_in[10], *c1_att = (const float*)d_in[11],
              *c1_bias = (const float*)d_in[12];
  const float *c2_Wl = (const float*)d_in[13], *c2_bl = (const float*)d_in[14],
              *c2_Wr = (const float*)d_in[15], *c2_br = (const float*)d_in[16],
              *c2_We = (const float*)d_in[17], *c2_att = (const float*)d_in[18],
              *c2_bias = (const float*)d_in[19];
  const float *gW = (const float*)d_in[20], *gb = (const float*)d_in[21],
              *g_gn = (const float*)d_in[22], *g_bt = (const float*)d_in[23];
  const float *fW = (const float*)d_in[24], *fb = (const float*)d_in[25],
              *f_gn = (const float*)d_in[26], *f_bt = (const float*)d_in[27];
  const float *dW = (const float*)d_in[28], *db = (const float*)d_in[29],
              *d_gn = (const float*)d_in[30], *d_bt = (const float*)d_in[31];
  const float *k1W = (const float*)d_in[32], *k1b = (const float*)d_in[33],
              *k1_gn = (const float*)d_in[34], *k1_bt = (const float*)d_in[35];
  const float *k2W = (const float*)d_in[36], *k2b = (const float*)d_in[37],
              *k2_gn = (const float*)d_in[38], *k2_bt = (const float*)d_in[39];
  const float *k3W = (const float*)d_in[40], *k3b = (const float*)d_in[41];

  const int N = in_sizes[0] / 32;       // 32768
  const int E = in_sizes[1] / 2;        // 262144
  const int G = in_sizes[4] / 2048;     // 1024
  const int FIN = 32, FPIN = 2048;
  const int DIN = in_sizes[5] / G;      // 200

  char* ws = (char*)d_ws;
  size_t off = 0;
  auto alloc = [&](size_t bytes) {
    void* p = ws + off;
    off = (off + bytes + 255) & ~(size_t)255;
    return p;
  };
  __hip_bfloat16* xlb    = (__hip_bfloat16*)alloc((size_t)N * HC * 2);  // 16 MB
  __hip_bfloat16* xrb    = (__hip_bfloat16*)alloc((size_t)N * HC * 2);  // 16 MB
  __hip_bfloat16* hb1    = (__hip_bfloat16*)alloc((size_t)N * HC * 2);  // 16 MB
  __hip_bfloat16* hb2    = (__hip_bfloat16*)alloc((size_t)N * HC * 2);  // 16 MB
  __hip_bfloat16* xbf    = (__hip_bfloat16*)alloc((size_t)N * FIN * 2);
  __hip_bfloat16* fpbf   = (__hip_bfloat16*)alloc((size_t)G * FPIN * 2); // 4 MB
  __hip_bfloat16* wt1    = (__hip_bfloat16*)alloc((size_t)512 * FIN * 2);
  __hip_bfloat16* wt2    = (__hip_bfloat16*)alloc((size_t)512 * HC * 2);
  __hip_bfloat16* fwt    = (__hip_bfloat16*)alloc((size_t)256 * FPIN * 2); // 1 MB
  __hip_bfloat16* descbf = (__hip_bfloat16*)alloc((size_t)G * 224 * 2);
  __hip_bfloat16* dwt    = (__hip_bfloat16*)alloc((size_t)64 * 224 * 2);
  __hip_bfloat16* k1wt   = (__hip_bfloat16*)alloc((size_t)192 * 384 * 2);
  __hip_bfloat16* zbuf   = (__hip_bfloat16*)alloc((size_t)G * 384 * 2);
  float* z1      = (float*)alloc((size_t)G * 192 * 4);
  float* P_fp    = (float*)alloc((size_t)4 * G * 256 * 4);             // 4 MB
  int*   deg     = (int*)alloc((size_t)N * 4);
  int*   csr_ptr = (int*)alloc((size_t)(N + 1) * 4);
  int*   cursor  = (int*)alloc((size_t)N * 4);
  int*   csr_src = (int*)alloc((size_t)E * 4);
  float* csr_ea  = (float*)alloc((size_t)E * 8 * 4);                  // 8 MB
  float* ea_mean = (float*)alloc((size_t)N * 8 * 4);                  // 1 MB
  int*   bsum    = (int*)alloc((size_t)64 * 4);
  (void)ws_size;

  const int* srcp = edge_index;
  const int* dstp = edge_index + E;
  const int nb = (N + 1023) / 1024;

  hipMemsetAsync(deg, 0, (size_t)N * 4, stream);

  // prep: conversions + weight transposes + padded desc + k1W^T + degree count
  {
    long total = (long)N * FIN + (long)G * FPIN + 512 * 32 + 512 * 256 +
                 (long)G * 224 + 64 * 224 + 192 * 384 + E;
    prep_kernel<<<(int)((total + 255) / 256), 256, 0, stream>>>(
        x, fp, c1_Wl, c1_Wr, c2_Wl, c2_Wr, desc, dW, k1W, dstp, deg,
        xbf, fpbf, wt1, wt2, descbf, dwt, k1wt, N, G, E, DIN);
  }
  transpose_fwt_kernel<<<dim3(2048 / 64, 256 / 64), 256, 0, stream>>>(fW, fwt);
  scan1_kernel<<<nb, 1024, 0, stream>>>(deg, csr_ptr, bsum, N);
  scan2_kernel<<<(N + 1 + 255) / 256, 256, 0, stream>>>(bsum, csr_ptr, cursor, N, nb);
  fill_kernel<<<(E + 255) / 256, 256, 0, stream>>>(srcp, dstp, edge_attr, cursor,
                                                   csr_src, csr_ea, E);
  eamean_kernel<<<(N * 8 + 255) / 256, 256, 0, stream>>>(csr_ea, csr_ptr, ea_mean, N);

  // fp branch: split-K MFMA (256 blocks) + epilogue -> zbuf[:,64:320]
  gemm_skb_kernel<<<dim3(G / 64, 4, 4), 256, 0, stream>>>(fpbf, fwt, P_fp,
                                                          G, 256, FPIN, FPIN / 4);
  fp_epilogue_kernel<<<(G * 256 + 255) / 256, 256, 0, stream>>>(P_fp, fb, f_gn, f_bt,
                                                                zbuf, G, 256, 4);
  // desc branch (bf16 MFMA, K padded to 224) -> zbuf[:,320:384]
  gemm_rb_kernel<<<dim3(G / 64, 1), 256, 0, stream>>>(descbf, dwt, db, d_gn, d_bt,
                                                      zbuf, G, 224, 384, 320, 1);

  // layer 1
  gemm_mfma_kernel<<<dim3(N / 128, 4), 256, 0, stream>>>(xbf, wt1, c1_bl, c1_br, xlb, xrb, N, FIN);
  gat_kernel<<<N / 2, 128, 0, stream>>>(xlb, xrb, csr_ea, csr_src, csr_ptr, ea_mean,
                                        c1_We, c1_att, c1_bias, hb1, N);
  // layer 2
  gemm_mfma_kernel<<<dim3(N / 128, 4), 256, 0, stream>>>(hb1, wt2, c2_bl, c2_br, xlb, xrb, N, HC);
  gat_kernel<<<N / 2, 128, 0, stream>>>(xlb, xrb, csr_ea, csr_src, csr_ptr, ea_mean,
                                        c2_We, c2_att, c2_bias, hb2, N);

  // fused pool + g branch -> zbuf[:,0:64]
  poolg_kernel<<<G, 256, 0, stream>>>(hb2, gW, gb, g_gn, g_bt, zbuf, N / G);

  // k1 (bf16 MFMA) -> z1 fp32
  gemm_rb_kernel<<<dim3(G / 64, 3), 256, 0, stream>>>(zbuf, k1wt, k1b, k1_gn, k1_bt,
                                                      z1, G, 384, 192, 0, 0);
  // k2+k3 head
  head23_kernel<<<G / 16, 256, 0, stream>>>(z1, k2W, k2b, k2_gn, k2_bt, k3W, k3b,
                                            (float*)d_out);
}